// Round 20
// baseline (151.267 us; speedup 1.0000x reference)
//
#include <hip/hip_runtime.h>
#include <math.h>

#define NN 4096
#define DD 512
#define NC 10
#define NG 2

#define BM 128
#define BN 128
#define BK 32
#define NT (DD / BK)       // 16 K-steps

#define TSLOT 512          // teacher bucket slot (4 tiles of 128); max cnt ~470
#define SSLOT 256          // student bucket slot (2 tiles of 128); max cnt ~250
#define TROWS (NC * TSLOT)        // 5120
#define SROWS (NC * NG * SSLOT)   // 5120
#define NTILES 320         // 100 TT + 60 SS + 160 TS (= 8 * 40)

typedef __bf16 bf16x8 __attribute__((ext_vector_type(8)));
typedef __bf16 bf16x4 __attribute__((ext_vector_type(4)));
typedef float f32x4 __attribute__((ext_vector_type(4)));

__device__ __forceinline__ void load_lds16(const __bf16* g, __bf16* l) {
    __builtin_amdgcn_global_load_lds((const __attribute__((address_space(1))) void*)g,
                                     (__attribute__((address_space(3))) void*)l, 16, 0, 0);
}

__device__ __forceinline__ float agent_ld(const float* p) {
    return __hip_atomic_load(p, __ATOMIC_RELAXED, __HIP_MEMORY_SCOPE_AGENT);
}

// ---------------------------------------------------------------------------
// Kernel 0: deterministic counting sort -> bucket-contiguous permutations.
// Wave 0: teacher by label (10 buckets, slot 512).
// Wave 1: student by 2*label+group (20 buckets, slot 256).
// Each lane owns a contiguous 64-row range; shfl exclusive scan per bucket
// gives stable ranks. Writes perm arrays + float cnts[30] for k_out/gram.
// ---------------------------------------------------------------------------
__global__ void k_sort(const int* __restrict__ labels, const int* __restrict__ groups,
                       int* __restrict__ perm_t, int* __restrict__ perm_s,
                       float* __restrict__ cnts) {
    int lane = threadIdx.x & 63;
    int w = threadIdx.x >> 6;
    if (w == 0) {
        int cl[NC] = {};
        for (int k = 0; k < 64; ++k) {
            int l = labels[lane * 64 + k];
#pragma unroll
            for (int c = 0; c < NC; ++c) cl[c] += (l == c) ? 1 : 0;
        }
        int ex[NC], tot[NC];
#pragma unroll
        for (int c = 0; c < NC; ++c) {
            int x = cl[c];
#pragma unroll
            for (int o = 1; o < 64; o <<= 1) {
                int v = __shfl_up(x, o);
                if (lane >= o) x += v;
            }
            ex[c] = x - cl[c];
            tot[c] = __shfl(x, 63);
        }
        int run[NC] = {};
        for (int k = 0; k < 64; ++k) {
            int row = lane * 64 + k;
            int l = labels[row];
#pragma unroll
            for (int c = 0; c < NC; ++c)
                if (l == c) {
                    int rank = ex[c] + run[c];
                    if (rank < TSLOT) perm_t[c * TSLOT + rank] = row;
                    run[c]++;
                }
        }
        if (lane == 0) {
#pragma unroll
            for (int c = 0; c < NC; ++c)
                cnts[c] = (float)((tot[c] < TSLOT) ? tot[c] : TSLOT);
        }
    } else if (w == 1) {
        int cl[NC * NG] = {};
        for (int k = 0; k < 64; ++k) {
            int i = lane * 64 + k;
            int b = 2 * labels[i] + groups[i];
#pragma unroll
            for (int c = 0; c < NC * NG; ++c) cl[c] += (b == c) ? 1 : 0;
        }
        int ex[NC * NG], tot[NC * NG];
#pragma unroll
        for (int c = 0; c < NC * NG; ++c) {
            int x = cl[c];
#pragma unroll
            for (int o = 1; o < 64; o <<= 1) {
                int v = __shfl_up(x, o);
                if (lane >= o) x += v;
            }
            ex[c] = x - cl[c];
            tot[c] = __shfl(x, 63);
        }
        int run[NC * NG] = {};
        for (int k = 0; k < 64; ++k) {
            int row = lane * 64 + k;
            int b = 2 * labels[row] + groups[row];
#pragma unroll
            for (int c = 0; c < NC * NG; ++c)
                if (b == c) {
                    int rank = ex[c] + run[c];
                    if (rank < SSLOT) perm_s[c * SSLOT + rank] = row;
                    run[c]++;
                }
        }
        if (lane == 0) {
#pragma unroll
            for (int c = 0; c < NC * NG; ++c)
                cnts[10 + c] = (float)((tot[c] < SSLOT) ? tot[c] : SSLOT);
        }
    }
}

// ---------------------------------------------------------------------------
// Kernel 1: gather-convert into PADDED bucket layout + padded norms (pads
// zeroed) + sigma machinery (blocks 0..63: colsums/ssq from ORIGINAL arrays,
// last block computes invscale — unchanged math, absmax-0-proven).
// 2560 blocks x 4 rows: rows [0,5120) teacher padded, [5120,10240) student.
// ---------------------------------------------------------------------------
__global__ void k_prep(const float* __restrict__ ft, const float* __restrict__ fs,
                       const int* __restrict__ perm_t, const int* __restrict__ perm_s,
                       __bf16* __restrict__ Tp, __bf16* __restrict__ Sp,
                       float* __restrict__ ntp, float* __restrict__ nsp,
                       const float* __restrict__ cnts,
                       float* __restrict__ psum, float* __restrict__ ssq,
                       float* __restrict__ gbkt, float* __restrict__ invscale,
                       unsigned int* __restrict__ cnt) {
    int tid = threadIdx.x;
    if (blockIdx.x == 0 && tid < 64) gbkt[tid] = 0.0f;

    int w = tid >> 6, lane = tid & 63;
    int r = blockIdx.x * 4 + w;               // 0..10239
    bool isT = r < TROWS;
    int rr = isT ? r : r - TROWS;
    int c  = isT ? (rr >> 9) : (rr >> 8);
    int j  = isT ? (rr & 511) : (rr & 255);
    int n  = (int)cnts[isT ? c : 10 + c];
    bool valid = j < n;
    int src = valid ? (isT ? perm_t[c * TSLOT + j] : perm_s[c * SSLOT + j]) : 0;
    const float* sp = (isT ? ft : fs) + (size_t)src * DD;
    __bf16* dp = (isT ? Tp : Sp) + (size_t)rr * DD;
    float s = 0.0f;
#pragma unroll
    for (int q = 0; q < 2; ++q) {
        float4 v;
        if (valid) v = ((const float4*)sp)[lane + 64 * q];
        else { v.x = 0.0f; v.y = 0.0f; v.z = 0.0f; v.w = 0.0f; }
        s += v.x * v.x + v.y * v.y + v.z * v.z + v.w * v.w;
        bf16x4 b4;
        b4[0] = (__bf16)v.x; b4[1] = (__bf16)v.y; b4[2] = (__bf16)v.z; b4[3] = (__bf16)v.w;
        *(bf16x4*)(dp + (lane + 64 * q) * 4) = b4;
    }
#pragma unroll
    for (int o = 32; o; o >>= 1) s += __shfl_xor(s, o);
    if (lane == 0) (isT ? ntp : nsp)[rr] = s;

    // ---- heavy sigma blocks (0..63): colsums + sumsq from ORIGINAL data ----
    if (blockIdx.x >= 64) return;
    int b = blockIdx.x;
    const float* srcm = (b < 32) ? ft : fs;
    int r0 = (b & 31) * 128;
    int c0 = tid, c1 = tid + 256;
    float a0 = 0.0f, a1 = 0.0f, sq = 0.0f;
    for (int rw = r0; rw < r0 + 128; ++rw) {
        float v0 = srcm[(size_t)rw * DD + c0];
        float v1 = srcm[(size_t)rw * DD + c1];
        a0 += v0; a1 += v1;
        sq += v0 * v0 + v1 * v1;
    }
    psum[(size_t)b * 512 + c0] = a0;
    psum[(size_t)b * 512 + c1] = a1;
#pragma unroll
    for (int o = 32; o; o >>= 1) sq += __shfl_xor(sq, o);
    __shared__ float redsq[4];
    if (lane == 0) redsq[w] = sq;
    __syncthreads();
    if (tid == 0) ssq[b] = redsq[0] + redsq[1] + redsq[2] + redsq[3];

    __shared__ int amLast;
    __threadfence();
    __syncthreads();
    if (tid == 0) amLast = (atomicAdd(cnt, 1u) == 63u) ? 1 : 0;
    __syncthreads();
    if (!amLast) return;
    __threadfence();

    __shared__ float red[8];
    float ssum = (tid < 64) ? agent_ld(&ssq[tid]) : 0.0f;
    float d = 0.0f;
    for (int col = tid; col < DD; col += 256) {
        float su = 0.0f, sv = 0.0f;
#pragma unroll
        for (int p = 0; p < 32; ++p) {
            su += agent_ld(&psum[(size_t)p * 512 + col]);
            sv += agent_ld(&psum[(size_t)(p + 32) * 512 + col]);
        }
        d += su * sv;
    }
#pragma unroll
    for (int o = 32; o; o >>= 1) { ssum += __shfl_xor(ssum, o); d += __shfl_xor(d, o); }
    if (lane == 0) { red[w] = ssum; red[w + 4] = d; }
    __syncthreads();
    if (tid == 0) {
        float S  = red[0] + red[1] + red[2] + red[3];
        float Dt = red[4] + red[5] + red[6] + red[7];
        float sigma = S / (float)NN - 2.0f * Dt / ((float)NN * (float)NN);
        invscale[0] = 1.0f / (2.0f * sigma);
    }
}

// ---------------------------------------------------------------------------
// Kernel 2: block-diagonal Grams. K-loop BYTE-IDENTICAL to round 16's best
// (128x128, 4 waves 2x2, wave tile 64x64, 3-buffer depth-2 counted-vmcnt,
// conflict-free [kq][row][8] LDS). Only 320 tiles (block-diagonal after
// bucket permutation): [0,100) TT (bucket c, triangle of 4x4 tiles),
// [100,160) SS (bucket b, triangle of 2x2), [160,320) TS (c x (ti,sj)).
// Epilogue: single bucket per tile; valid = in-bounds mask; sym tiles weight
// off-diagonal pairs x2 (mirror tile never enumerated); one atomic per block.
// swz = (bid&7)*40 + bid>>3 (320 = 8*40, bijective).
// ---------------------------------------------------------------------------
__global__ __launch_bounds__(256, 3) void k_gram_all(
    const __bf16* __restrict__ Tp, const __bf16* __restrict__ Sp,
    const float* __restrict__ ntp, const float* __restrict__ nsp,
    const float* __restrict__ cnts,
    const float* __restrict__ invscale_p, float* __restrict__ gbkt) {

    __shared__ __bf16 As[3][4 * 128 * 8];   // 8 KB per buffer
    __shared__ __bf16 Bs[3][4 * 128 * 8];
    __shared__ float wred[4];

    int swz = ((int)blockIdx.x & 7) * 40 + ((int)blockIdx.x >> 3);
    int mode, bkt, diag, tiv, tjv;
    const __bf16 *A, *B;
    const float *nA, *nB;
    int nrow, ncol;

    if (swz < 100) {                          // TT
        mode = 0;
        int c = swz / 10, k = swz % 10;
        int ti = 0;
        while (k >= 4 - ti) { k -= 4 - ti; ++ti; }
        int tj = ti + k;
        bkt = c; diag = (ti == tj); tiv = ti; tjv = tj;
        int rb = c * TSLOT + ti * 128, cb = c * TSLOT + tj * 128;
        A = Tp + (size_t)rb * DD; B = Tp + (size_t)cb * DD;
        nA = ntp + rb; nB = ntp + cb;
        int cntc = (int)cnts[c];
        nrow = cntc - ti * 128; ncol = cntc - tj * 128;
    } else if (swz < 160) {                   // SS
        mode = 1;
        int q = swz - 100;
        int b = q / 3, k = q % 3;
        int ti = (k == 2) ? 1 : 0;
        int tj = (k == 0) ? 0 : 1;
        bkt = 10 + b; diag = (ti == tj); tiv = ti; tjv = tj;
        int rb = b * SSLOT + ti * 128, cb = b * SSLOT + tj * 128;
        A = Sp + (size_t)rb * DD; B = Sp + (size_t)cb * DD;
        nA = nsp + rb; nB = nsp + cb;
        int cntb = (int)cnts[10 + b];
        nrow = cntb - ti * 128; ncol = cntb - tj * 128;
    } else {                                  // TS
        mode = 2;
        int q = swz - 160;
        int c = q >> 4; q &= 15;
        int ti = q >> 2, sj = q & 3;
        int g = sj >> 1, st = sj & 1;
        bkt = 30 + 2 * c + g; diag = 0; tiv = 0; tjv = 0;
        int rb = c * TSLOT + ti * 128;
        int cb = (2 * c + g) * SSLOT + st * 128;
        A = Tp + (size_t)rb * DD; B = Sp + (size_t)cb * DD;
        nA = ntp + rb; nB = nsp + cb;
        nrow = (int)cnts[c] - ti * 128;
        ncol = (int)cnts[10 + 2 * c + g] - st * 128;
    }
    nrow = (nrow < 0) ? 0 : ((nrow > 128) ? 128 : nrow);
    ncol = (ncol < 0) ? 0 : ((ncol > 128) ? 128 : ncol);

    int tid = threadIdx.x;
    int lane = tid & 63, wid = tid >> 6;
    int wr = wid >> 1, wc = wid & 1;          // 2 x 2 wave grid
    int l15 = lane & 15, l4 = lane >> 4;

    int ra = tid & 127;
    int qa = tid >> 7;                        // 0..1
    const __bf16* gA = A + (size_t)ra * DD + qa * 8;   // +16 = chunk qa+2
    const __bf16* gB = B + (size_t)ra * DD + qa * 8;

    f32x4 acc[4][4] = {};

#define STAGE(bb, tt)                                                          \
    do {                                                                       \
        int _k0 = (tt) * BK;                                                   \
        load_lds16(gA + _k0,      &As[(bb)][(size_t)tid * 8]);                 \
        load_lds16(gA + _k0 + 16, &As[(bb)][(size_t)(tid + 256) * 8]);         \
        load_lds16(gB + _k0,      &Bs[(bb)][(size_t)tid * 8]);                 \
        load_lds16(gB + _k0 + 16, &Bs[(bb)][(size_t)(tid + 256) * 8]);         \
    } while (0)

    STAGE(0, 0);
    STAGE(1, 1);
    asm volatile("s_waitcnt vmcnt(4)" ::: "memory");
    __builtin_amdgcn_s_barrier();
    __builtin_amdgcn_sched_barrier(0);

#pragma unroll
    for (int t = 0; t < NT; ++t) {
        int b = t % 3;
        bf16x8 af[4], bfr[4];
#pragma unroll
        for (int im = 0; im < 4; ++im)
            af[im] = *(const bf16x8*)&As[b][((size_t)l4 * 128 + wr * 64 + im * 16 + l15) * 8];
#pragma unroll
        for (int in = 0; in < 4; ++in)
            bfr[in] = *(const bf16x8*)&Bs[b][((size_t)l4 * 128 + wc * 64 + in * 16 + l15) * 8];
        if (t + 2 < NT) STAGE((t + 2) % 3, t + 2);
#pragma unroll
        for (int im = 0; im < 4; ++im)
#pragma unroll
            for (int in = 0; in < 4; ++in)
                acc[im][in] = __builtin_amdgcn_mfma_f32_16x16x32_bf16(af[im], bfr[in], acc[im][in], 0, 0, 0);
        if (t + 1 < NT) {
            if (t + 2 < NT) asm volatile("s_waitcnt vmcnt(4)" ::: "memory");
            else            asm volatile("s_waitcnt vmcnt(0)" ::: "memory");
            __builtin_amdgcn_s_barrier();
            __builtin_amdgcn_sched_barrier(0);
        }
    }
#undef STAGE

    // epilogue: single-bucket masked sum; sym off-diagonal pairs weight x2
    float inv_scale = invscale_p[0];
    float nBv[4];
#pragma unroll
    for (int in = 0; in < 4; ++in)
        nBv[in] = nB[wc * 64 + in * 16 + l15];
    float ssum = 0.0f;
#pragma unroll
    for (int im = 0; im < 4; ++im) {
#pragma unroll
        for (int j = 0; j < 4; ++j) {
            int rl = wr * 64 + im * 16 + l4 * 4 + j;   // local row 0..127
            float ni = nA[rl];
#pragma unroll
            for (int in = 0; in < 4; ++in) {
                int cl_ = wc * 64 + in * 16 + l15;     // local col 0..127
                float d = ni + nBv[in] - 2.0f * acc[im][in][j];
                d = fmaxf(d, 1e-12f);
                float kv = __expf(-d * inv_scale);
                bool v = (rl < nrow) && (cl_ < ncol);
                if (mode == 2) {
                    ssum += v ? kv : 0.0f;
                } else {
                    int rg = tiv * 128 + rl, cg = tjv * 128 + cl_;
                    float wgt = !v ? 0.0f
                              : (diag ? (cg > rg ? 2.0f : (cg == rg ? 1.0f : 0.0f))
                                      : 2.0f);
                    ssum += wgt * kv;
                }
            }
        }
    }
#pragma unroll
    for (int o = 1; o < 64; o <<= 1) ssum += __shfl_xor(ssum, o);
    if (lane == 0) wred[wid] = ssum;
    __syncthreads();
    if (tid == 0) atomicAdd(&gbkt[bkt], wred[0] + wred[1] + wred[2] + wred[3]);
}

// ---------------------------------------------------------------------------
// Kernel 3: slim final combine (unchanged from round 19).
// ---------------------------------------------------------------------------
__global__ void k_out(const float* __restrict__ cnts, const float* __restrict__ gbkt,
                      float* __restrict__ out) {
    __shared__ float sh[80];
    int tid = threadIdx.x;
    if (tid < 30) sh[tid] = cnts[tid];
    else if (tid < 80) sh[tid] = gbkt[tid - 30];
    __syncthreads();
    if (tid == 0) {
        float total = 0.0f;
        for (int c = 0; c < NC; ++c) {
            float ntc = sh[c];
            float sn = fmaxf(ntc, 1.0f);
            float meanTT = sh[30 + c] / (sn * sn);
            for (int g = 0; g < NG; ++g) {
                float nsg = sh[10 + 2 * c + g];
                float ss = fmaxf(nsg, 1.0f);
                float meanSS = sh[40 + 2 * c + g] / (ss * ss);
                float meanTS = sh[60 + 2 * c + g] / (sn * ss);
                if (ntc > 0.0f && nsg > 0.0f)
                    total += meanTT + meanSS - 2.0f * meanTS;
            }
        }
        out[0] = 0.5f * total;
    }
}

// ---------------------------------------------------------------------------
// workspace layout (bytes):
// [0, 5242880)          : Tp bf16 [5120][512]  (padded teacher, bucket slots 512)
// [5242880, 10485760)   : Sp bf16 [5120][512]  (padded student, bucket slots 256)
// floats from 10485760 (wsf):
//   +0      ntp[5120]     (padded teacher norms, pads 0)
//   +5120   nsp[5120]
//   +10240  gbkt[64]      (zeroed by prep block 0)
//   +10304  invscale[1]
//   +10305  cnt (uint)    (zeroed by hipMemsetAsync)
//   +10306  ssq[64]
//   +10370  cnts[30]      (written by k_sort)
//   +10400  perm_t[5120]  (int)
//   +15520  perm_s[5120]  (int)
//   +20640  psum[64*512]
// total ~10.7 MB
// ---------------------------------------------------------------------------
extern "C" void kernel_launch(void* const* d_in, const int* in_sizes, int n_in,
                              void* d_out, int out_size, void* d_ws, size_t ws_size,
                              hipStream_t stream) {
    const float* fs     = (const float*)d_in[0];
    const float* ft     = (const float*)d_in[1];
    const int*   groups = (const int*)d_in[2];
    const int*   labels = (const int*)d_in[3];

    __bf16* Tp = (__bf16*)d_ws;
    __bf16* Sp = (__bf16*)d_ws + (size_t)TROWS * DD;
    float* wsf  = (float*)((char*)d_ws + (size_t)(TROWS + SROWS) * DD * sizeof(__bf16));
    float* ntp  = wsf;
    float* nsp  = wsf + 5120;
    float* gbkt = wsf + 10240;
    float* invs = wsf + 10304;
    unsigned int* cnt = (unsigned int*)(wsf + 10305);
    float* ssq  = wsf + 10306;
    float* cnts = wsf + 10370;
    int* perm_t = (int*)(wsf + 10400);
    int* perm_s = (int*)(wsf + 15520);
    float* psum = wsf + 20640;

    hipMemsetAsync(cnt, 0, sizeof(unsigned int), stream);
    k_sort<<<1, 128, 0, stream>>>(labels, groups, perm_t, perm_s, cnts);
    k_prep<<<2560, 256, 0, stream>>>(ft, fs, perm_t, perm_s, Tp, Sp, ntp, nsp,
                                     cnts, psum, ssq, gbkt, invs, cnt);
    k_gram_all<<<NTILES, 256, 0, stream>>>(Tp, Sp, ntp, nsp, cnts, invs, gbkt);
    k_out<<<1, 128, 0, stream>>>(cnts, gbkt, (float*)d_out);
}

// Round 21
// 78.061 us; speedup vs baseline: 1.9378x; 1.9378x over previous
//
#include <hip/hip_runtime.h>
#include <math.h>

#define NN 4096
#define DD 512
#define NC 10
#define NG 2

#define BM 128
#define BN 128
#define BK 32
#define NT (DD / BK)       // 16 K-steps

#define TSLOT 512          // teacher bucket slot (4 tiles of 128); max cnt ~470
#define SSLOT 256          // student bucket slot (2 tiles of 128); max cnt ~250
#define TROWS (NC * TSLOT)        // 5120
#define SROWS (NC * NG * SSLOT)   // 5120
#define NTILES 320         // 100 TT + 60 SS + 160 TS (= 8 * 40)

typedef __bf16 bf16x8 __attribute__((ext_vector_type(8)));
typedef __bf16 bf16x4 __attribute__((ext_vector_type(4)));
typedef float f32x4 __attribute__((ext_vector_type(4)));

__device__ __forceinline__ void load_lds16(const __bf16* g, __bf16* l) {
    __builtin_amdgcn_global_load_lds((const __attribute__((address_space(1))) void*)g,
                                     (__attribute__((address_space(3))) void*)l, 16, 0, 0);
}

__device__ __forceinline__ float agent_ld(const float* p) {
    return __hip_atomic_load(p, __ATOMIC_RELAXED, __HIP_MEMORY_SCOPE_AGENT);
}

// ---------------------------------------------------------------------------
// Kernel 0: PARALLEL deterministic counting sort (stable by row index —
// produces the exact perm arrays round 20's serial version did).
// 1024 threads; thread t owns rows 4t..4t+3 (coalesced int4 loads).
// Per-thread register bucket counts (compile-time indices), wave shfl_up
// inclusive scans per bucket, cross-wave scan via LDS, then each thread
// writes its 4 perm entries. ~200 scan ops total vs r20's serial 64-deep
// latency chains (100.8 us measured -> ~4 us predicted).
// ---------------------------------------------------------------------------
__global__ __launch_bounds__(1024) void k_sort(
    const int* __restrict__ labels, const int* __restrict__ groups,
    int* __restrict__ perm_t, int* __restrict__ perm_s,
    float* __restrict__ cnts) {

    __shared__ int wtot[16][32];
    __shared__ int woff[16][32];

    int tid = threadIdx.x;
    int lane = tid & 63, w = tid >> 6;

    int4 lab = ((const int4*)labels)[tid];
    int4 grp = ((const int4*)groups)[tid];
    int l[4] = {lab.x, lab.y, lab.z, lab.w};
    int g[4] = {grp.x, grp.y, grp.z, grp.w};

    // per-thread bucket counts (registers, compile-time indexed)
    int cT[NC] = {}, cS[NC * NG] = {};
#pragma unroll
    for (int k = 0; k < 4; ++k) {
        int sb = 2 * l[k] + g[k];
#pragma unroll
        for (int c = 0; c < NC; ++c) cT[c] += (l[k] == c) ? 1 : 0;
#pragma unroll
        for (int c = 0; c < NC * NG; ++c) cS[c] += (sb == c) ? 1 : 0;
    }

    // wave-level inclusive scans -> per-thread exclusive offsets + wave totals
    int eT[NC], eS[NC * NG];
#pragma unroll
    for (int c = 0; c < NC; ++c) {
        int x = cT[c];
#pragma unroll
        for (int o = 1; o < 64; o <<= 1) { int v = __shfl_up(x, o); if (lane >= o) x += v; }
        eT[c] = x - cT[c];
        if (lane == 63) wtot[w][c] = x;
    }
#pragma unroll
    for (int c = 0; c < NC * NG; ++c) {
        int x = cS[c];
#pragma unroll
        for (int o = 1; o < 64; o <<= 1) { int v = __shfl_up(x, o); if (lane >= o) x += v; }
        eS[c] = x - cS[c];
        if (lane == 63) wtot[w][NC + c] = x;
    }
    __syncthreads();

    // cross-wave exclusive scan (threads 0..29, 16 summands each) + totals
    if (tid < NC + NC * NG) {
        int run = 0;
        for (int ww = 0; ww < 16; ++ww) { woff[ww][tid] = run; run += wtot[ww][tid]; }
        int slot = (tid < NC) ? TSLOT : SSLOT;
        cnts[tid] = (float)((run < slot) ? run : slot);
    }
    __syncthreads();

    // write perm entries (stable: row-index order within bucket)
    int runT[NC] = {}, runS[NC * NG] = {};
#pragma unroll
    for (int k = 0; k < 4; ++k) {
        int row = tid * 4 + k;
        int lb = l[k], sb = 2 * l[k] + g[k];
#pragma unroll
        for (int c = 0; c < NC; ++c)
            if (lb == c) {
                int rank = woff[w][c] + eT[c] + runT[c];
                if (rank < TSLOT) perm_t[c * TSLOT + rank] = row;
                runT[c]++;
            }
#pragma unroll
        for (int c = 0; c < NC * NG; ++c)
            if (sb == c) {
                int rank = woff[w][NC + c] + eS[c] + runS[c];
                if (rank < SSLOT) perm_s[c * SSLOT + rank] = row;
                runS[c]++;
            }
    }
}

// ---------------------------------------------------------------------------
// Kernel 1: gather-convert into PADDED bucket layout + padded norms (pads
// zeroed) + sigma machinery (blocks 0..63: colsums/ssq from ORIGINAL arrays,
// last block computes invscale). (unchanged from round 20)
// ---------------------------------------------------------------------------
__global__ void k_prep(const float* __restrict__ ft, const float* __restrict__ fs,
                       const int* __restrict__ perm_t, const int* __restrict__ perm_s,
                       __bf16* __restrict__ Tp, __bf16* __restrict__ Sp,
                       float* __restrict__ ntp, float* __restrict__ nsp,
                       const float* __restrict__ cnts,
                       float* __restrict__ psum, float* __restrict__ ssq,
                       float* __restrict__ gbkt, float* __restrict__ invscale,
                       unsigned int* __restrict__ cnt) {
    int tid = threadIdx.x;
    if (blockIdx.x == 0 && tid < 64) gbkt[tid] = 0.0f;

    int w = tid >> 6, lane = tid & 63;
    int r = blockIdx.x * 4 + w;               // 0..10239
    bool isT = r < TROWS;
    int rr = isT ? r : r - TROWS;
    int c  = isT ? (rr >> 9) : (rr >> 8);
    int j  = isT ? (rr & 511) : (rr & 255);
    int n  = (int)cnts[isT ? c : 10 + c];
    bool valid = j < n;
    int src = valid ? (isT ? perm_t[c * TSLOT + j] : perm_s[c * SSLOT + j]) : 0;
    const float* sp = (isT ? ft : fs) + (size_t)src * DD;
    __bf16* dp = (isT ? Tp : Sp) + (size_t)rr * DD;
    float s = 0.0f;
#pragma unroll
    for (int q = 0; q < 2; ++q) {
        float4 v;
        if (valid) v = ((const float4*)sp)[lane + 64 * q];
        else { v.x = 0.0f; v.y = 0.0f; v.z = 0.0f; v.w = 0.0f; }
        s += v.x * v.x + v.y * v.y + v.z * v.z + v.w * v.w;
        bf16x4 b4;
        b4[0] = (__bf16)v.x; b4[1] = (__bf16)v.y; b4[2] = (__bf16)v.z; b4[3] = (__bf16)v.w;
        *(bf16x4*)(dp + (lane + 64 * q) * 4) = b4;
    }
#pragma unroll
    for (int o = 32; o; o >>= 1) s += __shfl_xor(s, o);
    if (lane == 0) (isT ? ntp : nsp)[rr] = s;

    // ---- heavy sigma blocks (0..63): colsums + sumsq from ORIGINAL data ----
    if (blockIdx.x >= 64) return;
    int b = blockIdx.x;
    const float* srcm = (b < 32) ? ft : fs;
    int r0 = (b & 31) * 128;
    int c0 = tid, c1 = tid + 256;
    float a0 = 0.0f, a1 = 0.0f, sq = 0.0f;
    for (int rw = r0; rw < r0 + 128; ++rw) {
        float v0 = srcm[(size_t)rw * DD + c0];
        float v1 = srcm[(size_t)rw * DD + c1];
        a0 += v0; a1 += v1;
        sq += v0 * v0 + v1 * v1;
    }
    psum[(size_t)b * 512 + c0] = a0;
    psum[(size_t)b * 512 + c1] = a1;
#pragma unroll
    for (int o = 32; o; o >>= 1) sq += __shfl_xor(sq, o);
    __shared__ float redsq[4];
    if (lane == 0) redsq[w] = sq;
    __syncthreads();
    if (tid == 0) ssq[b] = redsq[0] + redsq[1] + redsq[2] + redsq[3];

    __shared__ int amLast;
    __threadfence();
    __syncthreads();
    if (tid == 0) amLast = (atomicAdd(cnt, 1u) == 63u) ? 1 : 0;
    __syncthreads();
    if (!amLast) return;
    __threadfence();

    __shared__ float red[8];
    float ssum = (tid < 64) ? agent_ld(&ssq[tid]) : 0.0f;
    float d = 0.0f;
    for (int col = tid; col < DD; col += 256) {
        float su = 0.0f, sv = 0.0f;
#pragma unroll
        for (int p = 0; p < 32; ++p) {
            su += agent_ld(&psum[(size_t)p * 512 + col]);
            sv += agent_ld(&psum[(size_t)(p + 32) * 512 + col]);
        }
        d += su * sv;
    }
#pragma unroll
    for (int o = 32; o; o >>= 1) { ssum += __shfl_xor(ssum, o); d += __shfl_xor(d, o); }
    if (lane == 0) { red[w] = ssum; red[w + 4] = d; }
    __syncthreads();
    if (tid == 0) {
        float S  = red[0] + red[1] + red[2] + red[3];
        float Dt = red[4] + red[5] + red[6] + red[7];
        float sigma = S / (float)NN - 2.0f * Dt / ((float)NN * (float)NN);
        invscale[0] = 1.0f / (2.0f * sigma);
    }
}

// ---------------------------------------------------------------------------
// Kernel 2: block-diagonal Grams. (unchanged from round 20: r16 K-loop,
// 320 tiles, single-bucket masked epilogue, one atomic per block)
// ---------------------------------------------------------------------------
__global__ __launch_bounds__(256, 3) void k_gram_all(
    const __bf16* __restrict__ Tp, const __bf16* __restrict__ Sp,
    const float* __restrict__ ntp, const float* __restrict__ nsp,
    const float* __restrict__ cnts,
    const float* __restrict__ invscale_p, float* __restrict__ gbkt) {

    __shared__ __bf16 As[3][4 * 128 * 8];   // 8 KB per buffer
    __shared__ __bf16 Bs[3][4 * 128 * 8];
    __shared__ float wred[4];

    int swz = ((int)blockIdx.x & 7) * 40 + ((int)blockIdx.x >> 3);
    int mode, bkt, diag, tiv, tjv;
    const __bf16 *A, *B;
    const float *nA, *nB;
    int nrow, ncol;

    if (swz < 100) {                          // TT
        mode = 0;
        int c = swz / 10, k = swz % 10;
        int ti = 0;
        while (k >= 4 - ti) { k -= 4 - ti; ++ti; }
        int tj = ti + k;
        bkt = c; diag = (ti == tj); tiv = ti; tjv = tj;
        int rb = c * TSLOT + ti * 128, cb = c * TSLOT + tj * 128;
        A = Tp + (size_t)rb * DD; B = Tp + (size_t)cb * DD;
        nA = ntp + rb; nB = ntp + cb;
        int cntc = (int)cnts[c];
        nrow = cntc - ti * 128; ncol = cntc - tj * 128;
    } else if (swz < 160) {                   // SS
        mode = 1;
        int q = swz - 100;
        int b = q / 3, k = q % 3;
        int ti = (k == 2) ? 1 : 0;
        int tj = (k == 0) ? 0 : 1;
        bkt = 10 + b; diag = (ti == tj); tiv = ti; tjv = tj;
        int rb = b * SSLOT + ti * 128, cb = b * SSLOT + tj * 128;
        A = Sp + (size_t)rb * DD; B = Sp + (size_t)cb * DD;
        nA = nsp + rb; nB = nsp + cb;
        int cntb = (int)cnts[10 + b];
        nrow = cntb - ti * 128; ncol = cntb - tj * 128;
    } else {                                  // TS
        mode = 2;
        int q = swz - 160;
        int c = q >> 4; q &= 15;
        int ti = q >> 2, sj = q & 3;
        int g = sj >> 1, st = sj & 1;
        bkt = 30 + 2 * c + g; diag = 0; tiv = 0; tjv = 0;
        int rb = c * TSLOT + ti * 128;
        int cb = (2 * c + g) * SSLOT + st * 128;
        A = Tp + (size_t)rb * DD; B = Sp + (size_t)cb * DD;
        nA = ntp + rb; nB = nsp + cb;
        nrow = (int)cnts[c] - ti * 128;
        ncol = (int)cnts[10 + 2 * c + g] - st * 128;
    }
    nrow = (nrow < 0) ? 0 : ((nrow > 128) ? 128 : nrow);
    ncol = (ncol < 0) ? 0 : ((ncol > 128) ? 128 : ncol);

    int tid = threadIdx.x;
    int lane = tid & 63, wid = tid >> 6;
    int wr = wid >> 1, wc = wid & 1;          // 2 x 2 wave grid
    int l15 = lane & 15, l4 = lane >> 4;

    int ra = tid & 127;
    int qa = tid >> 7;                        // 0..1
    const __bf16* gA = A + (size_t)ra * DD + qa * 8;   // +16 = chunk qa+2
    const __bf16* gB = B + (size_t)ra * DD + qa * 8;

    f32x4 acc[4][4] = {};

#define STAGE(bb, tt)                                                          \
    do {                                                                       \
        int _k0 = (tt) * BK;                                                   \
        load_lds16(gA + _k0,      &As[(bb)][(size_t)tid * 8]);                 \
        load_lds16(gA + _k0 + 16, &As[(bb)][(size_t)(tid + 256) * 8]);         \
        load_lds16(gB + _k0,      &Bs[(bb)][(size_t)tid * 8]);                 \
        load_lds16(gB + _k0 + 16, &Bs[(bb)][(size_t)(tid + 256) * 8]);         \
    } while (0)

    STAGE(0, 0);
    STAGE(1, 1);
    asm volatile("s_waitcnt vmcnt(4)" ::: "memory");
    __builtin_amdgcn_s_barrier();
    __builtin_amdgcn_sched_barrier(0);

#pragma unroll
    for (int t = 0; t < NT; ++t) {
        int b = t % 3;
        bf16x8 af[4], bfr[4];
#pragma unroll
        for (int im = 0; im < 4; ++im)
            af[im] = *(const bf16x8*)&As[b][((size_t)l4 * 128 + wr * 64 + im * 16 + l15) * 8];
#pragma unroll
        for (int in = 0; in < 4; ++in)
            bfr[in] = *(const bf16x8*)&Bs[b][((size_t)l4 * 128 + wc * 64 + in * 16 + l15) * 8];
        if (t + 2 < NT) STAGE((t + 2) % 3, t + 2);
#pragma unroll
        for (int im = 0; im < 4; ++im)
#pragma unroll
            for (int in = 0; in < 4; ++in)
                acc[im][in] = __builtin_amdgcn_mfma_f32_16x16x32_bf16(af[im], bfr[in], acc[im][in], 0, 0, 0);
        if (t + 1 < NT) {
            if (t + 2 < NT) asm volatile("s_waitcnt vmcnt(4)" ::: "memory");
            else            asm volatile("s_waitcnt vmcnt(0)" ::: "memory");
            __builtin_amdgcn_s_barrier();
            __builtin_amdgcn_sched_barrier(0);
        }
    }
#undef STAGE

    // epilogue: single-bucket masked sum; sym off-diagonal pairs weight x2
    float inv_scale = invscale_p[0];
    float nBv[4];
#pragma unroll
    for (int in = 0; in < 4; ++in)
        nBv[in] = nB[wc * 64 + in * 16 + l15];
    float ssum = 0.0f;
#pragma unroll
    for (int im = 0; im < 4; ++im) {
#pragma unroll
        for (int j = 0; j < 4; ++j) {
            int rl = wr * 64 + im * 16 + l4 * 4 + j;   // local row 0..127
            float ni = nA[rl];
#pragma unroll
            for (int in = 0; in < 4; ++in) {
                int cl_ = wc * 64 + in * 16 + l15;     // local col 0..127
                float d = ni + nBv[in] - 2.0f * acc[im][in][j];
                d = fmaxf(d, 1e-12f);
                float kv = __expf(-d * inv_scale);
                bool v = (rl < nrow) && (cl_ < ncol);
                if (mode == 2) {
                    ssum += v ? kv : 0.0f;
                } else {
                    int rg = tiv * 128 + rl, cg = tjv * 128 + cl_;
                    float wgt = !v ? 0.0f
                              : (diag ? (cg > rg ? 2.0f : (cg == rg ? 1.0f : 0.0f))
                                      : 2.0f);
                    ssum += wgt * kv;
                }
            }
        }
    }
#pragma unroll
    for (int o = 1; o < 64; o <<= 1) ssum += __shfl_xor(ssum, o);
    if (lane == 0) wred[wid] = ssum;
    __syncthreads();
    if (tid == 0) atomicAdd(&gbkt[bkt], wred[0] + wred[1] + wred[2] + wred[3]);
}

// ---------------------------------------------------------------------------
// Kernel 3: slim final combine (unchanged).
// ---------------------------------------------------------------------------
__global__ void k_out(const float* __restrict__ cnts, const float* __restrict__ gbkt,
                      float* __restrict__ out) {
    __shared__ float sh[80];
    int tid = threadIdx.x;
    if (tid < 30) sh[tid] = cnts[tid];
    else if (tid < 80) sh[tid] = gbkt[tid - 30];
    __syncthreads();
    if (tid == 0) {
        float total = 0.0f;
        for (int c = 0; c < NC; ++c) {
            float ntc = sh[c];
            float sn = fmaxf(ntc, 1.0f);
            float meanTT = sh[30 + c] / (sn * sn);
            for (int g = 0; g < NG; ++g) {
                float nsg = sh[10 + 2 * c + g];
                float ss = fmaxf(nsg, 1.0f);
                float meanSS = sh[40 + 2 * c + g] / (ss * ss);
                float meanTS = sh[60 + 2 * c + g] / (sn * ss);
                if (ntc > 0.0f && nsg > 0.0f)
                    total += meanTT + meanSS - 2.0f * meanTS;
            }
        }
        out[0] = 0.5f * total;
    }
}

// ---------------------------------------------------------------------------
// workspace layout (bytes):
// [0, 5242880)          : Tp bf16 [5120][512]  (padded teacher, bucket slots 512)
// [5242880, 10485760)   : Sp bf16 [5120][512]  (padded student, bucket slots 256)
// floats from 10485760 (wsf):
//   +0      ntp[5120]     (padded teacher norms, pads 0)
//   +5120   nsp[5120]
//   +10240  gbkt[64]      (zeroed by prep block 0)
//   +10304  invscale[1]
//   +10305  cnt (uint)    (zeroed by hipMemsetAsync)
//   +10306  ssq[64]
//   +10370  cnts[30]      (written by k_sort)
//   +10400  perm_t[5120]  (int)
//   +15520  perm_s[5120]  (int)
//   +20640  psum[64*512]
// total ~10.7 MB
// ---------------------------------------------------------------------------
extern "C" void kernel_launch(void* const* d_in, const int* in_sizes, int n_in,
                              void* d_out, int out_size, void* d_ws, size_t ws_size,
                              hipStream_t stream) {
    const float* fs     = (const float*)d_in[0];
    const float* ft     = (const float*)d_in[1];
    const int*   groups = (const int*)d_in[2];
    const int*   labels = (const int*)d_in[3];

    __bf16* Tp = (__bf16*)d_ws;
    __bf16* Sp = (__bf16*)d_ws + (size_t)TROWS * DD;
    float* wsf  = (float*)((char*)d_ws + (size_t)(TROWS + SROWS) * DD * sizeof(__bf16));
    float* ntp  = wsf;
    float* nsp  = wsf + 5120;
    float* gbkt = wsf + 10240;
    float* invs = wsf + 10304;
    unsigned int* cnt = (unsigned int*)(wsf + 10305);
    float* ssq  = wsf + 10306;
    float* cnts = wsf + 10370;
    int* perm_t = (int*)(wsf + 10400);
    int* perm_s = (int*)(wsf + 15520);
    float* psum = wsf + 20640;

    hipMemsetAsync(cnt, 0, sizeof(unsigned int), stream);
    k_sort<<<1, 1024, 0, stream>>>(labels, groups, perm_t, perm_s, cnts);
    k_prep<<<2560, 256, 0, stream>>>(ft, fs, perm_t, perm_s, Tp, Sp, ntp, nsp,
                                     cnts, psum, ssq, gbkt, invs, cnt);
    k_gram_all<<<NTILES, 256, 0, stream>>>(Tp, Sp, ntp, nsp, cnts, invs, gbkt);
    k_out<<<1, 128, 0, stream>>>(cnts, gbkt, (float*)d_out);
}

// Round 22
// 73.328 us; speedup vs baseline: 2.0629x; 1.0645x over previous
//
#include <hip/hip_runtime.h>
#include <math.h>

#define NN 4096
#define DD 512
#define NC 10
#define NG 2

#define BM 128
#define BN 128
#define BK 32
#define NT (DD / BK)       // 16 K-steps

#define TSLOT 512          // teacher bucket slot (4 tiles of 128); max cnt ~470
#define SSLOT 256          // student bucket slot (2 tiles of 128); max cnt ~250
#define TROWS (NC * TSLOT)        // 5120
#define SROWS (NC * NG * SSLOT)   // 5120
#define NTILES 320         // 100 TT + 60 SS + 160 TS (= 8 * 40)

typedef __bf16 bf16x8 __attribute__((ext_vector_type(8)));
typedef __bf16 bf16x4 __attribute__((ext_vector_type(4)));
typedef float f32x4 __attribute__((ext_vector_type(4)));

__device__ __forceinline__ void load_lds16(const __bf16* g, __bf16* l) {
    __builtin_amdgcn_global_load_lds((const __attribute__((address_space(1))) void*)g,
                                     (__attribute__((address_space(3))) void*)l, 16, 0, 0);
}

__device__ __forceinline__ float agent_ld(const float* p) {
    return __hip_atomic_load(p, __ATOMIC_RELAXED, __HIP_MEMORY_SCOPE_AGENT);
}

// ---------------------------------------------------------------------------
// Kernel 0: PARALLEL deterministic counting sort (unchanged from round 21)
// + thread 0 zeroes the k_prep completion counter (replaces the 4-byte
// hipMemsetAsync node, which cost ~40 us in graph replay). k_sort runs
// before k_prep in stream order -> visibility guaranteed at kernel boundary.
// ---------------------------------------------------------------------------
__global__ __launch_bounds__(1024) void k_sort(
    const int* __restrict__ labels, const int* __restrict__ groups,
    int* __restrict__ perm_t, int* __restrict__ perm_s,
    float* __restrict__ cnts, unsigned int* __restrict__ cnt) {

    __shared__ int wtot[16][32];
    __shared__ int woff[16][32];

    int tid = threadIdx.x;
    if (tid == 0) *cnt = 0u;
    int lane = tid & 63, w = tid >> 6;

    int4 lab = ((const int4*)labels)[tid];
    int4 grp = ((const int4*)groups)[tid];
    int l[4] = {lab.x, lab.y, lab.z, lab.w};
    int g[4] = {grp.x, grp.y, grp.z, grp.w};

    // per-thread bucket counts (registers, compile-time indexed)
    int cT[NC] = {}, cS[NC * NG] = {};
#pragma unroll
    for (int k = 0; k < 4; ++k) {
        int sb = 2 * l[k] + g[k];
#pragma unroll
        for (int c = 0; c < NC; ++c) cT[c] += (l[k] == c) ? 1 : 0;
#pragma unroll
        for (int c = 0; c < NC * NG; ++c) cS[c] += (sb == c) ? 1 : 0;
    }

    // wave-level inclusive scans -> per-thread exclusive offsets + wave totals
    int eT[NC], eS[NC * NG];
#pragma unroll
    for (int c = 0; c < NC; ++c) {
        int x = cT[c];
#pragma unroll
        for (int o = 1; o < 64; o <<= 1) { int v = __shfl_up(x, o); if (lane >= o) x += v; }
        eT[c] = x - cT[c];
        if (lane == 63) wtot[w][c] = x;
    }
#pragma unroll
    for (int c = 0; c < NC * NG; ++c) {
        int x = cS[c];
#pragma unroll
        for (int o = 1; o < 64; o <<= 1) { int v = __shfl_up(x, o); if (lane >= o) x += v; }
        eS[c] = x - cS[c];
        if (lane == 63) wtot[w][NC + c] = x;
    }
    __syncthreads();

    // cross-wave exclusive scan (threads 0..29, 16 summands each) + totals
    if (tid < NC + NC * NG) {
        int run = 0;
        for (int ww = 0; ww < 16; ++ww) { woff[ww][tid] = run; run += wtot[ww][tid]; }
        int slot = (tid < NC) ? TSLOT : SSLOT;
        cnts[tid] = (float)((run < slot) ? run : slot);
    }
    __syncthreads();

    // write perm entries (stable: row-index order within bucket)
    int runT[NC] = {}, runS[NC * NG] = {};
#pragma unroll
    for (int k = 0; k < 4; ++k) {
        int row = tid * 4 + k;
        int lb = l[k], sb = 2 * l[k] + g[k];
#pragma unroll
        for (int c = 0; c < NC; ++c)
            if (lb == c) {
                int rank = woff[w][c] + eT[c] + runT[c];
                if (rank < TSLOT) perm_t[c * TSLOT + rank] = row;
                runT[c]++;
            }
#pragma unroll
        for (int c = 0; c < NC * NG; ++c)
            if (sb == c) {
                int rank = woff[w][NC + c] + eS[c] + runS[c];
                if (rank < SSLOT) perm_s[c * SSLOT + rank] = row;
                runS[c]++;
            }
    }
}

// ---------------------------------------------------------------------------
// Kernel 1: gather-convert into PADDED bucket layout + padded norms (pads
// zeroed) + sigma machinery (blocks 0..63: colsums/ssq from ORIGINAL arrays,
// last block computes invscale). (unchanged from round 21)
// ---------------------------------------------------------------------------
__global__ void k_prep(const float* __restrict__ ft, const float* __restrict__ fs,
                       const int* __restrict__ perm_t, const int* __restrict__ perm_s,
                       __bf16* __restrict__ Tp, __bf16* __restrict__ Sp,
                       float* __restrict__ ntp, float* __restrict__ nsp,
                       const float* __restrict__ cnts,
                       float* __restrict__ psum, float* __restrict__ ssq,
                       float* __restrict__ gbkt, float* __restrict__ invscale,
                       unsigned int* __restrict__ cnt) {
    int tid = threadIdx.x;
    if (blockIdx.x == 0 && tid < 64) gbkt[tid] = 0.0f;

    int w = tid >> 6, lane = tid & 63;
    int r = blockIdx.x * 4 + w;               // 0..10239
    bool isT = r < TROWS;
    int rr = isT ? r : r - TROWS;
    int c  = isT ? (rr >> 9) : (rr >> 8);
    int j  = isT ? (rr & 511) : (rr & 255);
    int n  = (int)cnts[isT ? c : 10 + c];
    bool valid = j < n;
    int src = valid ? (isT ? perm_t[c * TSLOT + j] : perm_s[c * SSLOT + j]) : 0;
    const float* sp = (isT ? ft : fs) + (size_t)src * DD;
    __bf16* dp = (isT ? Tp : Sp) + (size_t)rr * DD;
    float s = 0.0f;
#pragma unroll
    for (int q = 0; q < 2; ++q) {
        float4 v;
        if (valid) v = ((const float4*)sp)[lane + 64 * q];
        else { v.x = 0.0f; v.y = 0.0f; v.z = 0.0f; v.w = 0.0f; }
        s += v.x * v.x + v.y * v.y + v.z * v.z + v.w * v.w;
        bf16x4 b4;
        b4[0] = (__bf16)v.x; b4[1] = (__bf16)v.y; b4[2] = (__bf16)v.z; b4[3] = (__bf16)v.w;
        *(bf16x4*)(dp + (lane + 64 * q) * 4) = b4;
    }
#pragma unroll
    for (int o = 32; o; o >>= 1) s += __shfl_xor(s, o);
    if (lane == 0) (isT ? ntp : nsp)[rr] = s;

    // ---- heavy sigma blocks (0..63): colsums + sumsq from ORIGINAL data ----
    if (blockIdx.x >= 64) return;
    int b = blockIdx.x;
    const float* srcm = (b < 32) ? ft : fs;
    int r0 = (b & 31) * 128;
    int c0 = tid, c1 = tid + 256;
    float a0 = 0.0f, a1 = 0.0f, sq = 0.0f;
    for (int rw = r0; rw < r0 + 128; ++rw) {
        float v0 = srcm[(size_t)rw * DD + c0];
        float v1 = srcm[(size_t)rw * DD + c1];
        a0 += v0; a1 += v1;
        sq += v0 * v0 + v1 * v1;
    }
    psum[(size_t)b * 512 + c0] = a0;
    psum[(size_t)b * 512 + c1] = a1;
#pragma unroll
    for (int o = 32; o; o >>= 1) sq += __shfl_xor(sq, o);
    __shared__ float redsq[4];
    if (lane == 0) redsq[w] = sq;
    __syncthreads();
    if (tid == 0) ssq[b] = redsq[0] + redsq[1] + redsq[2] + redsq[3];

    __shared__ int amLast;
    __threadfence();
    __syncthreads();
    if (tid == 0) amLast = (atomicAdd(cnt, 1u) == 63u) ? 1 : 0;
    __syncthreads();
    if (!amLast) return;
    __threadfence();

    __shared__ float red[8];
    float ssum = (tid < 64) ? agent_ld(&ssq[tid]) : 0.0f;
    float d = 0.0f;
    for (int col = tid; col < DD; col += 256) {
        float su = 0.0f, sv = 0.0f;
#pragma unroll
        for (int p = 0; p < 32; ++p) {
            su += agent_ld(&psum[(size_t)p * 512 + col]);
            sv += agent_ld(&psum[(size_t)(p + 32) * 512 + col]);
        }
        d += su * sv;
    }
#pragma unroll
    for (int o = 32; o; o >>= 1) { ssum += __shfl_xor(ssum, o); d += __shfl_xor(d, o); }
    if (lane == 0) { red[w] = ssum; red[w + 4] = d; }
    __syncthreads();
    if (tid == 0) {
        float S  = red[0] + red[1] + red[2] + red[3];
        float Dt = red[4] + red[5] + red[6] + red[7];
        float sigma = S / (float)NN - 2.0f * Dt / ((float)NN * (float)NN);
        invscale[0] = 1.0f / (2.0f * sigma);
    }
}

// ---------------------------------------------------------------------------
// Kernel 2: block-diagonal Grams. (unchanged from round 21: r16 K-loop,
// 320 tiles, single-bucket masked epilogue, one atomic per block)
// ---------------------------------------------------------------------------
__global__ __launch_bounds__(256, 3) void k_gram_all(
    const __bf16* __restrict__ Tp, const __bf16* __restrict__ Sp,
    const float* __restrict__ ntp, const float* __restrict__ nsp,
    const float* __restrict__ cnts,
    const float* __restrict__ invscale_p, float* __restrict__ gbkt) {

    __shared__ __bf16 As[3][4 * 128 * 8];   // 8 KB per buffer
    __shared__ __bf16 Bs[3][4 * 128 * 8];
    __shared__ float wred[4];

    int swz = ((int)blockIdx.x & 7) * 40 + ((int)blockIdx.x >> 3);
    int mode, bkt, diag, tiv, tjv;
    const __bf16 *A, *B;
    const float *nA, *nB;
    int nrow, ncol;

    if (swz < 100) {                          // TT
        mode = 0;
        int c = swz / 10, k = swz % 10;
        int ti = 0;
        while (k >= 4 - ti) { k -= 4 - ti; ++ti; }
        int tj = ti + k;
        bkt = c; diag = (ti == tj); tiv = ti; tjv = tj;
        int rb = c * TSLOT + ti * 128, cb = c * TSLOT + tj * 128;
        A = Tp + (size_t)rb * DD; B = Tp + (size_t)cb * DD;
        nA = ntp + rb; nB = ntp + cb;
        int cntc = (int)cnts[c];
        nrow = cntc - ti * 128; ncol = cntc - tj * 128;
    } else if (swz < 160) {                   // SS
        mode = 1;
        int q = swz - 100;
        int b = q / 3, k = q % 3;
        int ti = (k == 2) ? 1 : 0;
        int tj = (k == 0) ? 0 : 1;
        bkt = 10 + b; diag = (ti == tj); tiv = ti; tjv = tj;
        int rb = b * SSLOT + ti * 128, cb = b * SSLOT + tj * 128;
        A = Sp + (size_t)rb * DD; B = Sp + (size_t)cb * DD;
        nA = nsp + rb; nB = nsp + cb;
        int cntb = (int)cnts[10 + b];
        nrow = cntb - ti * 128; ncol = cntb - tj * 128;
    } else {                                  // TS
        mode = 2;
        int q = swz - 160;
        int c = q >> 4; q &= 15;
        int ti = q >> 2, sj = q & 3;
        int g = sj >> 1, st = sj & 1;
        bkt = 30 + 2 * c + g; diag = 0; tiv = 0; tjv = 0;
        int rb = c * TSLOT + ti * 128;
        int cb = (2 * c + g) * SSLOT + st * 128;
        A = Tp + (size_t)rb * DD; B = Sp + (size_t)cb * DD;
        nA = ntp + rb; nB = nsp + cb;
        nrow = (int)cnts[c] - ti * 128;
        ncol = (int)cnts[10 + 2 * c + g] - st * 128;
    }
    nrow = (nrow < 0) ? 0 : ((nrow > 128) ? 128 : nrow);
    ncol = (ncol < 0) ? 0 : ((ncol > 128) ? 128 : ncol);

    int tid = threadIdx.x;
    int lane = tid & 63, wid = tid >> 6;
    int wr = wid >> 1, wc = wid & 1;          // 2 x 2 wave grid
    int l15 = lane & 15, l4 = lane >> 4;

    int ra = tid & 127;
    int qa = tid >> 7;                        // 0..1
    const __bf16* gA = A + (size_t)ra * DD + qa * 8;   // +16 = chunk qa+2
    const __bf16* gB = B + (size_t)ra * DD + qa * 8;

    f32x4 acc[4][4] = {};

#define STAGE(bb, tt)                                                          \
    do {                                                                       \
        int _k0 = (tt) * BK;                                                   \
        load_lds16(gA + _k0,      &As[(bb)][(size_t)tid * 8]);                 \
        load_lds16(gA + _k0 + 16, &As[(bb)][(size_t)(tid + 256) * 8]);         \
        load_lds16(gB + _k0,      &Bs[(bb)][(size_t)tid * 8]);                 \
        load_lds16(gB + _k0 + 16, &Bs[(bb)][(size_t)(tid + 256) * 8]);         \
    } while (0)

    STAGE(0, 0);
    STAGE(1, 1);
    asm volatile("s_waitcnt vmcnt(4)" ::: "memory");
    __builtin_amdgcn_s_barrier();
    __builtin_amdgcn_sched_barrier(0);

#pragma unroll
    for (int t = 0; t < NT; ++t) {
        int b = t % 3;
        bf16x8 af[4], bfr[4];
#pragma unroll
        for (int im = 0; im < 4; ++im)
            af[im] = *(const bf16x8*)&As[b][((size_t)l4 * 128 + wr * 64 + im * 16 + l15) * 8];
#pragma unroll
        for (int in = 0; in < 4; ++in)
            bfr[in] = *(const bf16x8*)&Bs[b][((size_t)l4 * 128 + wc * 64 + in * 16 + l15) * 8];
        if (t + 2 < NT) STAGE((t + 2) % 3, t + 2);
#pragma unroll
        for (int im = 0; im < 4; ++im)
#pragma unroll
            for (int in = 0; in < 4; ++in)
                acc[im][in] = __builtin_amdgcn_mfma_f32_16x16x32_bf16(af[im], bfr[in], acc[im][in], 0, 0, 0);
        if (t + 1 < NT) {
            if (t + 2 < NT) asm volatile("s_waitcnt vmcnt(4)" ::: "memory");
            else            asm volatile("s_waitcnt vmcnt(0)" ::: "memory");
            __builtin_amdgcn_s_barrier();
            __builtin_amdgcn_sched_barrier(0);
        }
    }
#undef STAGE

    // epilogue: single-bucket masked sum; sym off-diagonal pairs weight x2
    float inv_scale = invscale_p[0];
    float nBv[4];
#pragma unroll
    for (int in = 0; in < 4; ++in)
        nBv[in] = nB[wc * 64 + in * 16 + l15];
    float ssum = 0.0f;
#pragma unroll
    for (int im = 0; im < 4; ++im) {
#pragma unroll
        for (int j = 0; j < 4; ++j) {
            int rl = wr * 64 + im * 16 + l4 * 4 + j;   // local row 0..127
            float ni = nA[rl];
#pragma unroll
            for (int in = 0; in < 4; ++in) {
                int cl_ = wc * 64 + in * 16 + l15;     // local col 0..127
                float d = ni + nBv[in] - 2.0f * acc[im][in][j];
                d = fmaxf(d, 1e-12f);
                float kv = __expf(-d * inv_scale);
                bool v = (rl < nrow) && (cl_ < ncol);
                if (mode == 2) {
                    ssum += v ? kv : 0.0f;
                } else {
                    int rg = tiv * 128 + rl, cg = tjv * 128 + cl_;
                    float wgt = !v ? 0.0f
                              : (diag ? (cg > rg ? 2.0f : (cg == rg ? 1.0f : 0.0f))
                                      : 2.0f);
                    ssum += wgt * kv;
                }
            }
        }
    }
#pragma unroll
    for (int o = 1; o < 64; o <<= 1) ssum += __shfl_xor(ssum, o);
    if (lane == 0) wred[wid] = ssum;
    __syncthreads();
    if (tid == 0) atomicAdd(&gbkt[bkt], wred[0] + wred[1] + wred[2] + wred[3]);
}

// ---------------------------------------------------------------------------
// Kernel 3: slim final combine (unchanged).
// ---------------------------------------------------------------------------
__global__ void k_out(const float* __restrict__ cnts, const float* __restrict__ gbkt,
                      float* __restrict__ out) {
    __shared__ float sh[80];
    int tid = threadIdx.x;
    if (tid < 30) sh[tid] = cnts[tid];
    else if (tid < 80) sh[tid] = gbkt[tid - 30];
    __syncthreads();
    if (tid == 0) {
        float total = 0.0f;
        for (int c = 0; c < NC; ++c) {
            float ntc = sh[c];
            float sn = fmaxf(ntc, 1.0f);
            float meanTT = sh[30 + c] / (sn * sn);
            for (int g = 0; g < NG; ++g) {
                float nsg = sh[10 + 2 * c + g];
                float ss = fmaxf(nsg, 1.0f);
                float meanSS = sh[40 + 2 * c + g] / (ss * ss);
                float meanTS = sh[60 + 2 * c + g] / (sn * ss);
                if (ntc > 0.0f && nsg > 0.0f)
                    total += meanTT + meanSS - 2.0f * meanTS;
            }
        }
        out[0] = 0.5f * total;
    }
}

// ---------------------------------------------------------------------------
// workspace layout (bytes):
// [0, 5242880)          : Tp bf16 [5120][512]  (padded teacher, bucket slots 512)
// [5242880, 10485760)   : Sp bf16 [5120][512]  (padded student, bucket slots 256)
// floats from 10485760 (wsf):
//   +0      ntp[5120]     (padded teacher norms, pads 0)
//   +5120   nsp[5120]
//   +10240  gbkt[64]      (zeroed by prep block 0)
//   +10304  invscale[1]
//   +10305  cnt (uint)    (zeroed by k_sort thread 0)
//   +10306  ssq[64]
//   +10370  cnts[30]      (written by k_sort)
//   +10400  perm_t[5120]  (int)
//   +15520  perm_s[5120]  (int)
//   +20640  psum[64*512]
// total ~10.7 MB
// ---------------------------------------------------------------------------
extern "C" void kernel_launch(void* const* d_in, const int* in_sizes, int n_in,
                              void* d_out, int out_size, void* d_ws, size_t ws_size,
                              hipStream_t stream) {
    const float* fs     = (const float*)d_in[0];
    const float* ft     = (const float*)d_in[1];
    const int*   groups = (const int*)d_in[2];
    const int*   labels = (const int*)d_in[3];

    __bf16* Tp = (__bf16*)d_ws;
    __bf16* Sp = (__bf16*)d_ws + (size_t)TROWS * DD;
    float* wsf  = (float*)((char*)d_ws + (size_t)(TROWS + SROWS) * DD * sizeof(__bf16));
    float* ntp  = wsf;
    float* nsp  = wsf + 5120;
    float* gbkt = wsf + 10240;
    float* invs = wsf + 10304;
    unsigned int* cnt = (unsigned int*)(wsf + 10305);
    float* ssq  = wsf + 10306;
    float* cnts = wsf + 10370;
    int* perm_t = (int*)(wsf + 10400);
    int* perm_s = (int*)(wsf + 15520);
    float* psum = wsf + 20640;

    k_sort<<<1, 1024, 0, stream>>>(labels, groups, perm_t, perm_s, cnts, cnt);
    k_prep<<<2560, 256, 0, stream>>>(ft, fs, perm_t, perm_s, Tp, Sp, ntp, nsp,
                                     cnts, psum, ssq, gbkt, invs, cnt);
    k_gram_all<<<NTILES, 256, 0, stream>>>(Tp, Sp, ntp, nsp, cnts, invs, gbkt);
    k_out<<<1, 128, 0, stream>>>(cnts, gbkt, (float*)d_out);
}

// Round 23
// 60.039 us; speedup vs baseline: 2.5195x; 1.2213x over previous
//
#include <hip/hip_runtime.h>
#include <math.h>

#define NN 4096
#define DD 512
#define NC 10
#define NG 2

#define BM 128
#define BN 128
#define BK 32
#define NT (DD / BK)       // 16 K-steps

#define TSLOT 512          // teacher bucket slot (4 tiles of 128); max cnt ~470
#define SSLOT 256          // student bucket slot (2 tiles of 128); max cnt ~250
#define TROWS (NC * TSLOT)        // 5120
#define SROWS (NC * NG * SSLOT)   // 5120
#define NTILES 320         // 100 TT + 60 SS + 160 TS (= 8 * 40)

typedef __bf16 bf16x8 __attribute__((ext_vector_type(8)));
typedef __bf16 bf16x4 __attribute__((ext_vector_type(4)));
typedef float f32x4 __attribute__((ext_vector_type(4)));

__device__ __forceinline__ void load_lds16(const __bf16* g, __bf16* l) {
    __builtin_amdgcn_global_load_lds((const __attribute__((address_space(1))) void*)g,
                                     (__attribute__((address_space(3))) void*)l, 16, 0, 0);
}

// ---------------------------------------------------------------------------
// Kernel 0 (fused): blocks 0..63 = column sums + sumsq partials (r22's exact
// 256-active-thread arithmetic -> identical psum/ssq values); block 64 = the
// parallel counting sort (r22's exact code). Sort latency hides under the
// 16 MB of colsum reads. No fence/counter protocol anywhere.
// ---------------------------------------------------------------------------
__global__ __launch_bounds__(1024) void k_sortcol(
    const int* __restrict__ labels, const int* __restrict__ groups,
    const float* __restrict__ ft, const float* __restrict__ fs,
    int* __restrict__ perm_t, int* __restrict__ perm_s,
    float* __restrict__ cnts, float* __restrict__ psum, float* __restrict__ ssq) {

    __shared__ int wtot[16][32];
    __shared__ int woff[16][32];
    __shared__ float redsq[4];

    int tid = threadIdx.x;

    if (blockIdx.x < 64) {
        // ---- colsums + ssq, 256 active threads (r22 arithmetic) ----
        if (tid >= 256) return;
        int b = blockIdx.x;
        int w = tid >> 6, lane = tid & 63;
        const float* srcm = (b < 32) ? ft : fs;
        int r0 = (b & 31) * 128;
        int c0 = tid, c1 = tid + 256;
        float a0 = 0.0f, a1 = 0.0f, sq = 0.0f;
        for (int rw = r0; rw < r0 + 128; ++rw) {
            float v0 = srcm[(size_t)rw * DD + c0];
            float v1 = srcm[(size_t)rw * DD + c1];
            a0 += v0; a1 += v1;
            sq += v0 * v0 + v1 * v1;
        }
        psum[(size_t)b * 512 + c0] = a0;
        psum[(size_t)b * 512 + c1] = a1;
#pragma unroll
        for (int o = 32; o; o >>= 1) sq += __shfl_xor(sq, o);
        if (lane == 0) redsq[w] = sq;
        __syncthreads();
        if (tid == 0) ssq[b] = redsq[0] + redsq[1] + redsq[2] + redsq[3];
        return;
    }

    // ---- block 64: parallel deterministic counting sort (r22 code) ----
    int lane = tid & 63, w = tid >> 6;

    int4 lab = ((const int4*)labels)[tid];
    int4 grp = ((const int4*)groups)[tid];
    int l[4] = {lab.x, lab.y, lab.z, lab.w};
    int g[4] = {grp.x, grp.y, grp.z, grp.w};

    int cT[NC] = {}, cS[NC * NG] = {};
#pragma unroll
    for (int k = 0; k < 4; ++k) {
        int sb = 2 * l[k] + g[k];
#pragma unroll
        for (int c = 0; c < NC; ++c) cT[c] += (l[k] == c) ? 1 : 0;
#pragma unroll
        for (int c = 0; c < NC * NG; ++c) cS[c] += (sb == c) ? 1 : 0;
    }

    int eT[NC], eS[NC * NG];
#pragma unroll
    for (int c = 0; c < NC; ++c) {
        int x = cT[c];
#pragma unroll
        for (int o = 1; o < 64; o <<= 1) { int v = __shfl_up(x, o); if (lane >= o) x += v; }
        eT[c] = x - cT[c];
        if (lane == 63) wtot[w][c] = x;
    }
#pragma unroll
    for (int c = 0; c < NC * NG; ++c) {
        int x = cS[c];
#pragma unroll
        for (int o = 1; o < 64; o <<= 1) { int v = __shfl_up(x, o); if (lane >= o) x += v; }
        eS[c] = x - cS[c];
        if (lane == 63) wtot[w][NC + c] = x;
    }
    __syncthreads();

    if (tid < NC + NC * NG) {
        int run = 0;
        for (int ww = 0; ww < 16; ++ww) { woff[ww][tid] = run; run += wtot[ww][tid]; }
        int slot = (tid < NC) ? TSLOT : SSLOT;
        cnts[tid] = (float)((run < slot) ? run : slot);
    }
    __syncthreads();

    int runT[NC] = {}, runS[NC * NG] = {};
#pragma unroll
    for (int k = 0; k < 4; ++k) {
        int row = tid * 4 + k;
        int lb = l[k], sb = 2 * l[k] + g[k];
#pragma unroll
        for (int c = 0; c < NC; ++c)
            if (lb == c) {
                int rank = woff[w][c] + eT[c] + runT[c];
                if (rank < TSLOT) perm_t[c * TSLOT + rank] = row;
                runT[c]++;
            }
#pragma unroll
        for (int c = 0; c < NC * NG; ++c)
            if (sb == c) {
                int rank = woff[w][NC + c] + eS[c] + runS[c];
                if (rank < SSLOT) perm_s[c * SSLOT + rank] = row;
                runS[c]++;
            }
    }
}

// ---------------------------------------------------------------------------
// Kernel 1: gather-convert into PADDED bucket layout + padded norms.
// Block 0 zeroes gbkt; block 1 additionally computes invscale from psum/ssq
// (kernel boundary after k_sortcol guarantees visibility — no fence needed;
// same summation code/order as r22 -> identical sigma).
// ---------------------------------------------------------------------------
__global__ void k_prep(const float* __restrict__ ft, const float* __restrict__ fs,
                       const int* __restrict__ perm_t, const int* __restrict__ perm_s,
                       __bf16* __restrict__ Tp, __bf16* __restrict__ Sp,
                       float* __restrict__ ntp, float* __restrict__ nsp,
                       const float* __restrict__ cnts,
                       const float* __restrict__ psum, const float* __restrict__ ssq,
                       float* __restrict__ gbkt, float* __restrict__ invscale) {
    int tid = threadIdx.x;
    if (blockIdx.x == 0 && tid < 64) gbkt[tid] = 0.0f;

    int w = tid >> 6, lane = tid & 63;
    int r = blockIdx.x * 4 + w;               // 0..10239
    bool isT = r < TROWS;
    int rr = isT ? r : r - TROWS;
    int c  = isT ? (rr >> 9) : (rr >> 8);
    int j  = isT ? (rr & 511) : (rr & 255);
    int n  = (int)cnts[isT ? c : 10 + c];
    bool valid = j < n;
    int src = valid ? (isT ? perm_t[c * TSLOT + j] : perm_s[c * SSLOT + j]) : 0;
    const float* sp = (isT ? ft : fs) + (size_t)src * DD;
    __bf16* dp = (isT ? Tp : Sp) + (size_t)rr * DD;
    float s = 0.0f;
#pragma unroll
    for (int q = 0; q < 2; ++q) {
        float4 v;
        if (valid) v = ((const float4*)sp)[lane + 64 * q];
        else { v.x = 0.0f; v.y = 0.0f; v.z = 0.0f; v.w = 0.0f; }
        s += v.x * v.x + v.y * v.y + v.z * v.z + v.w * v.w;
        bf16x4 b4;
        b4[0] = (__bf16)v.x; b4[1] = (__bf16)v.y; b4[2] = (__bf16)v.z; b4[3] = (__bf16)v.w;
        *(bf16x4*)(dp + (lane + 64 * q) * 4) = b4;
    }
#pragma unroll
    for (int o = 32; o; o >>= 1) s += __shfl_xor(s, o);
    if (lane == 0) (isT ? ntp : nsp)[rr] = s;

    // ---- block 1: sigma (closed form) -> invscale ----
    if (blockIdx.x != 1) return;
    __shared__ float red[8];
    float ssum = (tid < 64) ? ssq[tid] : 0.0f;
    float d = 0.0f;
    for (int col = tid; col < DD; col += 256) {
        float su = 0.0f, sv = 0.0f;
#pragma unroll
        for (int p = 0; p < 32; ++p) {
            su += psum[(size_t)p * 512 + col];
            sv += psum[(size_t)(p + 32) * 512 + col];
        }
        d += su * sv;
    }
#pragma unroll
    for (int o = 32; o; o >>= 1) { ssum += __shfl_xor(ssum, o); d += __shfl_xor(d, o); }
    if (lane == 0) { red[w] = ssum; red[w + 4] = d; }
    __syncthreads();
    if (tid == 0) {
        float S  = red[0] + red[1] + red[2] + red[3];
        float Dt = red[4] + red[5] + red[6] + red[7];
        float sigma = S / (float)NN - 2.0f * Dt / ((float)NN * (float)NN);
        invscale[0] = 1.0f / (2.0f * sigma);
    }
}

// ---------------------------------------------------------------------------
// Kernel 2: block-diagonal Grams. (byte-identical to rounds 20-22: r16
// K-loop, 320 tiles, single-bucket masked epilogue, one atomic per block)
// ---------------------------------------------------------------------------
__global__ __launch_bounds__(256, 3) void k_gram_all(
    const __bf16* __restrict__ Tp, const __bf16* __restrict__ Sp,
    const float* __restrict__ ntp, const float* __restrict__ nsp,
    const float* __restrict__ cnts,
    const float* __restrict__ invscale_p, float* __restrict__ gbkt) {

    __shared__ __bf16 As[3][4 * 128 * 8];   // 8 KB per buffer
    __shared__ __bf16 Bs[3][4 * 128 * 8];
    __shared__ float wred[4];

    int swz = ((int)blockIdx.x & 7) * 40 + ((int)blockIdx.x >> 3);
    int mode, bkt, diag, tiv, tjv;
    const __bf16 *A, *B;
    const float *nA, *nB;
    int nrow, ncol;

    if (swz < 100) {                          // TT
        mode = 0;
        int c = swz / 10, k = swz % 10;
        int ti = 0;
        while (k >= 4 - ti) { k -= 4 - ti; ++ti; }
        int tj = ti + k;
        bkt = c; diag = (ti == tj); tiv = ti; tjv = tj;
        int rb = c * TSLOT + ti * 128, cb = c * TSLOT + tj * 128;
        A = Tp + (size_t)rb * DD; B = Tp + (size_t)cb * DD;
        nA = ntp + rb; nB = ntp + cb;
        int cntc = (int)cnts[c];
        nrow = cntc - ti * 128; ncol = cntc - tj * 128;
    } else if (swz < 160) {                   // SS
        mode = 1;
        int q = swz - 100;
        int b = q / 3, k = q % 3;
        int ti = (k == 2) ? 1 : 0;
        int tj = (k == 0) ? 0 : 1;
        bkt = 10 + b; diag = (ti == tj); tiv = ti; tjv = tj;
        int rb = b * SSLOT + ti * 128, cb = b * SSLOT + tj * 128;
        A = Sp + (size_t)rb * DD; B = Sp + (size_t)cb * DD;
        nA = nsp + rb; nB = nsp + cb;
        int cntb = (int)cnts[10 + b];
        nrow = cntb - ti * 128; ncol = cntb - tj * 128;
    } else {                                  // TS
        mode = 2;
        int q = swz - 160;
        int c = q >> 4; q &= 15;
        int ti = q >> 2, sj = q & 3;
        int g = sj >> 1, st = sj & 1;
        bkt = 30 + 2 * c + g; diag = 0; tiv = 0; tjv = 0;
        int rb = c * TSLOT + ti * 128;
        int cb = (2 * c + g) * SSLOT + st * 128;
        A = Tp + (size_t)rb * DD; B = Sp + (size_t)cb * DD;
        nA = ntp + rb; nB = nsp + cb;
        nrow = (int)cnts[c] - ti * 128;
        ncol = (int)cnts[10 + 2 * c + g] - st * 128;
    }
    nrow = (nrow < 0) ? 0 : ((nrow > 128) ? 128 : nrow);
    ncol = (ncol < 0) ? 0 : ((ncol > 128) ? 128 : ncol);

    int tid = threadIdx.x;
    int lane = tid & 63, wid = tid >> 6;
    int wr = wid >> 1, wc = wid & 1;          // 2 x 2 wave grid
    int l15 = lane & 15, l4 = lane >> 4;

    int ra = tid & 127;
    int qa = tid >> 7;                        // 0..1
    const __bf16* gA = A + (size_t)ra * DD + qa * 8;   // +16 = chunk qa+2
    const __bf16* gB = B + (size_t)ra * DD + qa * 8;

    f32x4 acc[4][4] = {};

#define STAGE(bb, tt)                                                          \
    do {                                                                       \
        int _k0 = (tt) * BK;                                                   \
        load_lds16(gA + _k0,      &As[(bb)][(size_t)tid * 8]);                 \
        load_lds16(gA + _k0 + 16, &As[(bb)][(size_t)(tid + 256) * 8]);         \
        load_lds16(gB + _k0,      &Bs[(bb)][(size_t)tid * 8]);                 \
        load_lds16(gB + _k0 + 16, &Bs[(bb)][(size_t)(tid + 256) * 8]);         \
    } while (0)

    STAGE(0, 0);
    STAGE(1, 1);
    asm volatile("s_waitcnt vmcnt(4)" ::: "memory");
    __builtin_amdgcn_s_barrier();
    __builtin_amdgcn_sched_barrier(0);

#pragma unroll
    for (int t = 0; t < NT; ++t) {
        int b = t % 3;
        bf16x8 af[4], bfr[4];
#pragma unroll
        for (int im = 0; im < 4; ++im)
            af[im] = *(const bf16x8*)&As[b][((size_t)l4 * 128 + wr * 64 + im * 16 + l15) * 8];
#pragma unroll
        for (int in = 0; in < 4; ++in)
            bfr[in] = *(const bf16x8*)&Bs[b][((size_t)l4 * 128 + wc * 64 + in * 16 + l15) * 8];
        if (t + 2 < NT) STAGE((t + 2) % 3, t + 2);
#pragma unroll
        for (int im = 0; im < 4; ++im)
#pragma unroll
            for (int in = 0; in < 4; ++in)
                acc[im][in] = __builtin_amdgcn_mfma_f32_16x16x32_bf16(af[im], bfr[in], acc[im][in], 0, 0, 0);
        if (t + 1 < NT) {
            if (t + 2 < NT) asm volatile("s_waitcnt vmcnt(4)" ::: "memory");
            else            asm volatile("s_waitcnt vmcnt(0)" ::: "memory");
            __builtin_amdgcn_s_barrier();
            __builtin_amdgcn_sched_barrier(0);
        }
    }
#undef STAGE

    // epilogue: single-bucket masked sum; sym off-diagonal pairs weight x2
    float inv_scale = invscale_p[0];
    float nBv[4];
#pragma unroll
    for (int in = 0; in < 4; ++in)
        nBv[in] = nB[wc * 64 + in * 16 + l15];
    float ssum = 0.0f;
#pragma unroll
    for (int im = 0; im < 4; ++im) {
#pragma unroll
        for (int j = 0; j < 4; ++j) {
            int rl = wr * 64 + im * 16 + l4 * 4 + j;   // local row 0..127
            float ni = nA[rl];
#pragma unroll
            for (int in = 0; in < 4; ++in) {
                int cl_ = wc * 64 + in * 16 + l15;     // local col 0..127
                float d = ni + nBv[in] - 2.0f * acc[im][in][j];
                d = fmaxf(d, 1e-12f);
                float kv = __expf(-d * inv_scale);
                bool v = (rl < nrow) && (cl_ < ncol);
                if (mode == 2) {
                    ssum += v ? kv : 0.0f;
                } else {
                    int rg = tiv * 128 + rl, cg = tjv * 128 + cl_;
                    float wgt = !v ? 0.0f
                              : (diag ? (cg > rg ? 2.0f : (cg == rg ? 1.0f : 0.0f))
                                      : 2.0f);
                    ssum += wgt * kv;
                }
            }
        }
    }
#pragma unroll
    for (int o = 1; o < 64; o <<= 1) ssum += __shfl_xor(ssum, o);
    if (lane == 0) wred[wid] = ssum;
    __syncthreads();
    if (tid == 0) atomicAdd(&gbkt[bkt], wred[0] + wred[1] + wred[2] + wred[3]);
}

// ---------------------------------------------------------------------------
// Kernel 3: slim final combine (unchanged).
// ---------------------------------------------------------------------------
__global__ void k_out(const float* __restrict__ cnts, const float* __restrict__ gbkt,
                      float* __restrict__ out) {
    __shared__ float sh[80];
    int tid = threadIdx.x;
    if (tid < 30) sh[tid] = cnts[tid];
    else if (tid < 80) sh[tid] = gbkt[tid - 30];
    __syncthreads();
    if (tid == 0) {
        float total = 0.0f;
        for (int c = 0; c < NC; ++c) {
            float ntc = sh[c];
            float sn = fmaxf(ntc, 1.0f);
            float meanTT = sh[30 + c] / (sn * sn);
            for (int g = 0; g < NG; ++g) {
                float nsg = sh[10 + 2 * c + g];
                float ss = fmaxf(nsg, 1.0f);
                float meanSS = sh[40 + 2 * c + g] / (ss * ss);
                float meanTS = sh[60 + 2 * c + g] / (sn * ss);
                if (ntc > 0.0f && nsg > 0.0f)
                    total += meanTT + meanSS - 2.0f * meanTS;
            }
        }
        out[0] = 0.5f * total;
    }
}

// ---------------------------------------------------------------------------
// workspace layout (bytes):
// [0, 5242880)          : Tp bf16 [5120][512]  (padded teacher, bucket slots 512)
// [5242880, 10485760)   : Sp bf16 [5120][512]  (padded student, bucket slots 256)
// floats from 10485760 (wsf):
//   +0      ntp[5120]
//   +5120   nsp[5120]
//   +10240  gbkt[64]      (zeroed by prep block 0)
//   +10304  invscale[1]   (written by prep block 1)
//   +10305  (unused)
//   +10306  ssq[64]
//   +10370  cnts[30]      (written by k_sortcol block 64)
//   +10400  perm_t[5120]  (int)
//   +15520  perm_s[5120]  (int)
//   +20640  psum[64*512]
// total ~10.7 MB
// ---------------------------------------------------------------------------
extern "C" void kernel_launch(void* const* d_in, const int* in_sizes, int n_in,
                              void* d_out, int out_size, void* d_ws, size_t ws_size,
                              hipStream_t stream) {
    const float* fs     = (const float*)d_in[0];
    const float* ft     = (const float*)d_in[1];
    const int*   groups = (const int*)d_in[2];
    const int*   labels = (const int*)d_in[3];

    __bf16* Tp = (__bf16*)d_ws;
    __bf16* Sp = (__bf16*)d_ws + (size_t)TROWS * DD;
    float* wsf  = (float*)((char*)d_ws + (size_t)(TROWS + SROWS) * DD * sizeof(__bf16));
    float* ntp  = wsf;
    float* nsp  = wsf + 5120;
    float* gbkt = wsf + 10240;
    float* invs = wsf + 10304;
    float* ssq  = wsf + 10306;
    float* cnts = wsf + 10370;
    int* perm_t = (int*)(wsf + 10400);
    int* perm_s = (int*)(wsf + 15520);
    float* psum = wsf + 20640;

    k_sortcol<<<65, 1024, 0, stream>>>(labels, groups, ft, fs,
                                       perm_t, perm_s, cnts, psum, ssq);
    k_prep<<<2560, 256, 0, stream>>>(ft, fs, perm_t, perm_s, Tp, Sp, ntp, nsp,
                                     cnts, psum, ssq, gbkt, invs);
    k_gram_all<<<NTILES, 256, 0, stream>>>(Tp, Sp, ntp, nsp, cnts, invs, gbkt);
    k_out<<<1, 128, 0, stream>>>(cnts, gbkt, (float*)d_out);
}

// Round 24
// 58.642 us; speedup vs baseline: 2.5795x; 1.0238x over previous
//
#include <hip/hip_runtime.h>
#include <math.h>

#define NN 4096
#define DD 512
#define NC 10
#define NG 2

#define BM 256
#define BN 128
#define BK 32
#define NT (DD / BK)       // 16 K-steps

#define TSLOT 512          // teacher bucket slot (2 row-tiles of 256)
#define SSLOT 256          // student bucket slot (1 row-tile of 256)
#define TROWS (NC * TSLOT)        // 5120
#define SROWS (NC * NG * SSLOT)   // 5120
#define NTILES 180         // 60 TT + 40 SS + 80 TS (single generation < 256 CUs)

typedef __bf16 bf16x8 __attribute__((ext_vector_type(8)));
typedef __bf16 bf16x4 __attribute__((ext_vector_type(4)));
typedef float f32x4 __attribute__((ext_vector_type(4)));

__device__ __forceinline__ void load_lds16(const __bf16* g, __bf16* l) {
    __builtin_amdgcn_global_load_lds((const __attribute__((address_space(1))) void*)g,
                                     (__attribute__((address_space(3))) void*)l, 16, 0, 0);
}

// ---------------------------------------------------------------------------
// Kernel 0 (fused): blocks 0..63 = column sums + sumsq partials; block 64 =
// parallel counting sort. (byte-identical to round 23)
// ---------------------------------------------------------------------------
__global__ __launch_bounds__(1024) void k_sortcol(
    const int* __restrict__ labels, const int* __restrict__ groups,
    const float* __restrict__ ft, const float* __restrict__ fs,
    int* __restrict__ perm_t, int* __restrict__ perm_s,
    float* __restrict__ cnts, float* __restrict__ psum, float* __restrict__ ssq) {

    __shared__ int wtot[16][32];
    __shared__ int woff[16][32];
    __shared__ float redsq[4];

    int tid = threadIdx.x;

    if (blockIdx.x < 64) {
        if (tid >= 256) return;
        int b = blockIdx.x;
        int w = tid >> 6, lane = tid & 63;
        const float* srcm = (b < 32) ? ft : fs;
        int r0 = (b & 31) * 128;
        int c0 = tid, c1 = tid + 256;
        float a0 = 0.0f, a1 = 0.0f, sq = 0.0f;
        for (int rw = r0; rw < r0 + 128; ++rw) {
            float v0 = srcm[(size_t)rw * DD + c0];
            float v1 = srcm[(size_t)rw * DD + c1];
            a0 += v0; a1 += v1;
            sq += v0 * v0 + v1 * v1;
        }
        psum[(size_t)b * 512 + c0] = a0;
        psum[(size_t)b * 512 + c1] = a1;
#pragma unroll
        for (int o = 32; o; o >>= 1) sq += __shfl_xor(sq, o);
        if (lane == 0) redsq[w] = sq;
        __syncthreads();
        if (tid == 0) ssq[b] = redsq[0] + redsq[1] + redsq[2] + redsq[3];
        return;
    }

    int lane = tid & 63, w = tid >> 6;

    int4 lab = ((const int4*)labels)[tid];
    int4 grp = ((const int4*)groups)[tid];
    int l[4] = {lab.x, lab.y, lab.z, lab.w};
    int g[4] = {grp.x, grp.y, grp.z, grp.w};

    int cT[NC] = {}, cS[NC * NG] = {};
#pragma unroll
    for (int k = 0; k < 4; ++k) {
        int sb = 2 * l[k] + g[k];
#pragma unroll
        for (int c = 0; c < NC; ++c) cT[c] += (l[k] == c) ? 1 : 0;
#pragma unroll
        for (int c = 0; c < NC * NG; ++c) cS[c] += (sb == c) ? 1 : 0;
    }

    int eT[NC], eS[NC * NG];
#pragma unroll
    for (int c = 0; c < NC; ++c) {
        int x = cT[c];
#pragma unroll
        for (int o = 1; o < 64; o <<= 1) { int v = __shfl_up(x, o); if (lane >= o) x += v; }
        eT[c] = x - cT[c];
        if (lane == 63) wtot[w][c] = x;
    }
#pragma unroll
    for (int c = 0; c < NC * NG; ++c) {
        int x = cS[c];
#pragma unroll
        for (int o = 1; o < 64; o <<= 1) { int v = __shfl_up(x, o); if (lane >= o) x += v; }
        eS[c] = x - cS[c];
        if (lane == 63) wtot[w][NC + c] = x;
    }
    __syncthreads();

    if (tid < NC + NC * NG) {
        int run = 0;
        for (int ww = 0; ww < 16; ++ww) { woff[ww][tid] = run; run += wtot[ww][tid]; }
        int slot = (tid < NC) ? TSLOT : SSLOT;
        cnts[tid] = (float)((run < slot) ? run : slot);
    }
    __syncthreads();

    int runT[NC] = {}, runS[NC * NG] = {};
#pragma unroll
    for (int k = 0; k < 4; ++k) {
        int row = tid * 4 + k;
        int lb = l[k], sb = 2 * l[k] + g[k];
#pragma unroll
        for (int c = 0; c < NC; ++c)
            if (lb == c) {
                int rank = woff[w][c] + eT[c] + runT[c];
                if (rank < TSLOT) perm_t[c * TSLOT + rank] = row;
                runT[c]++;
            }
#pragma unroll
        for (int c = 0; c < NC * NG; ++c)
            if (sb == c) {
                int rank = woff[w][NC + c] + eS[c] + runS[c];
                if (rank < SSLOT) perm_s[c * SSLOT + rank] = row;
                runS[c]++;
            }
    }
}

// ---------------------------------------------------------------------------
// Kernel 1: gather-convert + padded norms; block 0 zeroes gbkt; block 1
// computes invscale. (byte-identical to round 23)
// ---------------------------------------------------------------------------
__global__ void k_prep(const float* __restrict__ ft, const float* __restrict__ fs,
                       const int* __restrict__ perm_t, const int* __restrict__ perm_s,
                       __bf16* __restrict__ Tp, __bf16* __restrict__ Sp,
                       float* __restrict__ ntp, float* __restrict__ nsp,
                       const float* __restrict__ cnts,
                       const float* __restrict__ psum, const float* __restrict__ ssq,
                       float* __restrict__ gbkt, float* __restrict__ invscale) {
    int tid = threadIdx.x;
    if (blockIdx.x == 0 && tid < 64) gbkt[tid] = 0.0f;

    int w = tid >> 6, lane = tid & 63;
    int r = blockIdx.x * 4 + w;               // 0..10239
    bool isT = r < TROWS;
    int rr = isT ? r : r - TROWS;
    int c  = isT ? (rr >> 9) : (rr >> 8);
    int j  = isT ? (rr & 511) : (rr & 255);
    int n  = (int)cnts[isT ? c : 10 + c];
    bool valid = j < n;
    int src = valid ? (isT ? perm_t[c * TSLOT + j] : perm_s[c * SSLOT + j]) : 0;
    const float* sp = (isT ? ft : fs) + (size_t)src * DD;
    __bf16* dp = (isT ? Tp : Sp) + (size_t)rr * DD;
    float s = 0.0f;
#pragma unroll
    for (int q = 0; q < 2; ++q) {
        float4 v;
        if (valid) v = ((const float4*)sp)[lane + 64 * q];
        else { v.x = 0.0f; v.y = 0.0f; v.z = 0.0f; v.w = 0.0f; }
        s += v.x * v.x + v.y * v.y + v.z * v.z + v.w * v.w;
        bf16x4 b4;
        b4[0] = (__bf16)v.x; b4[1] = (__bf16)v.y; b4[2] = (__bf16)v.z; b4[3] = (__bf16)v.w;
        *(bf16x4*)(dp + (lane + 64 * q) * 4) = b4;
    }
#pragma unroll
    for (int o = 32; o; o >>= 1) s += __shfl_xor(s, o);
    if (lane == 0) (isT ? ntp : nsp)[rr] = s;

    if (blockIdx.x != 1) return;
    __shared__ float red[8];
    float ssum = (tid < 64) ? ssq[tid] : 0.0f;
    float d = 0.0f;
    for (int col = tid; col < DD; col += 256) {
        float su = 0.0f, sv = 0.0f;
#pragma unroll
        for (int p = 0; p < 32; ++p) {
            su += psum[(size_t)p * 512 + col];
            sv += psum[(size_t)(p + 32) * 512 + col];
        }
        d += su * sv;
    }
#pragma unroll
    for (int o = 32; o; o >>= 1) { ssum += __shfl_xor(ssum, o); d += __shfl_xor(d, o); }
    if (lane == 0) { red[w] = ssum; red[w + 4] = d; }
    __syncthreads();
    if (tid == 0) {
        float S  = red[0] + red[1] + red[2] + red[3];
        float Dt = red[4] + red[5] + red[6] + red[7];
        float sigma = S / (float)NN - 2.0f * Dt / ((float)NN * (float)NN);
        invscale[0] = 1.0f / (2.0f * sigma);
    }
}

// ---------------------------------------------------------------------------
// Kernel 2: block-diagonal Grams, SINGLE-GENERATION: 180 tiles of 256x128
// (< 256 CUs -> makespan = one tile). 8 waves (4Mx2N stacked: wr=wid>>1,
// wc=wid&1), wave tile 64x64 (acc[4][4], r4-verified geometry), r15's
// 3-buffer depth-2 counted-vmcnt pipeline (3 loads/thread -> steady vmcnt(3)).
// Tiles: [0,60) TT: bucket c, (ti,tj) in {(0,0..3),(1,2),(1,3)} — tiles with
// any cg>=rg element; [60,100) SS: bucket b, tj in {0,1}; [100,180) TS:
// (c, ti, g, st). Sym weight rule (shape-independent): cg>rg -> 2, == -> 1,
// < -> 0; each unordered pair counted exactly once. One atomic per block.
// ---------------------------------------------------------------------------
__global__ __launch_bounds__(512, 2) void k_gram_all(
    const __bf16* __restrict__ Tp, const __bf16* __restrict__ Sp,
    const float* __restrict__ ntp, const float* __restrict__ nsp,
    const float* __restrict__ cnts,
    const float* __restrict__ invscale_p, float* __restrict__ gbkt) {

    __shared__ __bf16 As[3][4 * 256 * 8];   // 16 KB per buffer
    __shared__ __bf16 Bs[3][4 * 128 * 8];   // 8 KB per buffer
    __shared__ float wred[8];

    int swz = (int)blockIdx.x;
    int mode, bkt, ti, tj;
    const __bf16 *A, *B;
    const float *nA, *nB;
    int nrow, ncol;

    if (swz < 60) {                           // TT: 6 tiles/bucket
        mode = 0;
        int c = swz / 6, r6 = swz % 6;
        ti = (r6 >= 4) ? 1 : 0;
        tj = (r6 < 4) ? r6 : (r6 - 2);
        bkt = c;
        int rb = c * TSLOT + ti * 256, cb = c * TSLOT + tj * 128;
        A = Tp + (size_t)rb * DD; B = Tp + (size_t)cb * DD;
        nA = ntp + rb; nB = ntp + cb;
        int cntc = (int)cnts[c];
        nrow = cntc - ti * 256; ncol = cntc - tj * 128;
    } else if (swz < 100) {                   // SS: 2 tiles/bucket
        mode = 1;
        int q = swz - 60;
        int b = q >> 1;
        ti = 0; tj = q & 1;
        bkt = 10 + b;
        int rb = b * SSLOT, cb = b * SSLOT + tj * 128;
        A = Sp + (size_t)rb * DD; B = Sp + (size_t)cb * DD;
        nA = nsp + rb; nB = nsp + cb;
        int cntb = (int)cnts[10 + b];
        nrow = cntb; ncol = cntb - tj * 128;
    } else {                                  // TS: 8 tiles per class c
        mode = 2;
        int q = swz - 100;
        int c = q >> 3, rem = q & 7;
        ti = rem >> 2;
        int g = (rem >> 1) & 1, st = rem & 1;
        tj = 0;
        bkt = 30 + 2 * c + g;
        int rb = c * TSLOT + ti * 256;
        int cb = (2 * c + g) * SSLOT + st * 128;
        A = Tp + (size_t)rb * DD; B = Sp + (size_t)cb * DD;
        nA = ntp + rb; nB = nsp + cb;
        nrow = (int)cnts[c] - ti * 256;
        ncol = (int)cnts[10 + 2 * c + g] - st * 128;
    }
    nrow = (nrow < 0) ? 0 : ((nrow > 256) ? 256 : nrow);
    ncol = (ncol < 0) ? 0 : ((ncol > 128) ? 128 : ncol);

    int tid = threadIdx.x;
    int lane = tid & 63, wid = tid >> 6;
    int wr = wid >> 1, wc = wid & 1;          // 4 row-waves x 2 col-waves
    int l15 = lane & 15, l4 = lane >> 4;

    // staging (r4 pattern): A slots tid, tid+512 (row=tid&255, kq=tid>>8,+2);
    // B slot tid (row=tid&127, kq=tid>>7). 3 loads/thread/tile.
    const __bf16* gA = A + (size_t)(tid & 255) * DD + (tid >> 8) * 8;
    const __bf16* gB = B + (size_t)(tid & 127) * DD + (tid >> 7) * 8;

    f32x4 acc[4][4] = {};

#define STAGE(bb, tt)                                                          \
    do {                                                                       \
        int _k0 = (tt) * BK;                                                   \
        load_lds16(gA + _k0,      &As[(bb)][(size_t)tid * 8]);                 \
        load_lds16(gA + _k0 + 16, &As[(bb)][(size_t)(tid + 512) * 8]);         \
        load_lds16(gB + _k0,      &Bs[(bb)][(size_t)tid * 8]);                 \
    } while (0)

    STAGE(0, 0);
    STAGE(1, 1);
    asm volatile("s_waitcnt vmcnt(3)" ::: "memory");
    __builtin_amdgcn_s_barrier();
    __builtin_amdgcn_sched_barrier(0);

#pragma unroll
    for (int t = 0; t < NT; ++t) {
        int b = t % 3;
        bf16x8 af[4], bfr[4];
#pragma unroll
        for (int im = 0; im < 4; ++im)
            af[im] = *(const bf16x8*)&As[b][((size_t)l4 * 256 + wr * 64 + im * 16 + l15) * 8];
#pragma unroll
        for (int in = 0; in < 4; ++in)
            bfr[in] = *(const bf16x8*)&Bs[b][((size_t)l4 * 128 + wc * 64 + in * 16 + l15) * 8];
        if (t + 2 < NT) STAGE((t + 2) % 3, t + 2);
#pragma unroll
        for (int im = 0; im < 4; ++im)
#pragma unroll
            for (int in = 0; in < 4; ++in)
                acc[im][in] = __builtin_amdgcn_mfma_f32_16x16x32_bf16(af[im], bfr[in], acc[im][in], 0, 0, 0);
        if (t + 1 < NT) {
            if (t + 2 < NT) asm volatile("s_waitcnt vmcnt(3)" ::: "memory");
            else            asm volatile("s_waitcnt vmcnt(0)" ::: "memory");
            __builtin_amdgcn_s_barrier();
            __builtin_amdgcn_sched_barrier(0);
        }
    }
#undef STAGE

    // epilogue: masked bucket sum; uniform sym weight rule on global indices
    float inv_scale = invscale_p[0];
    float nBv[4];
#pragma unroll
    for (int in = 0; in < 4; ++in)
        nBv[in] = nB[wc * 64 + in * 16 + l15];
    float ssum = 0.0f;
#pragma unroll
    for (int im = 0; im < 4; ++im) {
#pragma unroll
        for (int j = 0; j < 4; ++j) {
            int rl = wr * 64 + im * 16 + l4 * 4 + j;   // local row 0..255
            float ni = nA[rl];
#pragma unroll
            for (int in = 0; in < 4; ++in) {
                int cl_ = wc * 64 + in * 16 + l15;     // local col 0..127
                float d = ni + nBv[in] - 2.0f * acc[im][in][j];
                d = fmaxf(d, 1e-12f);
                float kv = __expf(-d * inv_scale);
                bool v = (rl < nrow) && (cl_ < ncol);
                if (mode == 2) {
                    ssum += v ? kv : 0.0f;
                } else {
                    int rg = ti * 256 + rl, cg = tj * 128 + cl_;
                    float wgt = !v ? 0.0f
                              : (cg > rg ? 2.0f : (cg == rg ? 1.0f : 0.0f));
                    ssum += wgt * kv;
                }
            }
        }
    }
#pragma unroll
    for (int o = 1; o < 64; o <<= 1) ssum += __shfl_xor(ssum, o);
    if (lane == 0) wred[wid] = ssum;
    __syncthreads();
    if (tid == 0) {
        float tot = 0.0f;
#pragma unroll
        for (int ww = 0; ww < 8; ++ww) tot += wred[ww];
        atomicAdd(&gbkt[bkt], tot);
    }
}

// ---------------------------------------------------------------------------
// Kernel 3: slim final combine (unchanged).
// ---------------------------------------------------------------------------
__global__ void k_out(const float* __restrict__ cnts, const float* __restrict__ gbkt,
                      float* __restrict__ out) {
    __shared__ float sh[80];
    int tid = threadIdx.x;
    if (tid < 30) sh[tid] = cnts[tid];
    else if (tid < 80) sh[tid] = gbkt[tid - 30];
    __syncthreads();
    if (tid == 0) {
        float total = 0.0f;
        for (int c = 0; c < NC; ++c) {
            float ntc = sh[c];
            float sn = fmaxf(ntc, 1.0f);
            float meanTT = sh[30 + c] / (sn * sn);
            for (int g = 0; g < NG; ++g) {
                float nsg = sh[10 + 2 * c + g];
                float ss = fmaxf(nsg, 1.0f);
                float meanSS = sh[40 + 2 * c + g] / (ss * ss);
                float meanTS = sh[60 + 2 * c + g] / (sn * ss);
                if (ntc > 0.0f && nsg > 0.0f)
                    total += meanTT + meanSS - 2.0f * meanTS;
            }
        }
        out[0] = 0.5f * total;
    }
}

// ---------------------------------------------------------------------------
// workspace layout (bytes):
// [0, 5242880)          : Tp bf16 [5120][512]
// [5242880, 10485760)   : Sp bf16 [5120][512]
// floats from 10485760 (wsf):
//   +0      ntp[5120]
//   +5120   nsp[5120]
//   +10240  gbkt[64]      (zeroed by prep block 0)
//   +10304  invscale[1]   (written by prep block 1)
//   +10306  ssq[64]
//   +10370  cnts[30]      (written by k_sortcol block 64)
//   +10400  perm_t[5120]  (int)
//   +15520  perm_s[5120]  (int)
//   +20640  psum[64*512]
// total ~10.7 MB
// ---------------------------------------------------------------------------
extern "C" void kernel_launch(void* const* d_in, const int* in_sizes, int n_in,
                              void* d_out, int out_size, void* d_ws, size_t ws_size,
                              hipStream_t stream) {
    const float* fs     = (const float*)d_in[0];
    const float* ft     = (const float*)d_in[1];
    const int*   groups = (const int*)d_in[2];
    const int*   labels = (const int*)d_in[3];

    __bf16* Tp = (__bf16*)d_ws;
    __bf16* Sp = (__bf16*)d_ws + (size_t)TROWS * DD;
    float* wsf  = (float*)((char*)d_ws + (size_t)(TROWS + SROWS) * DD * sizeof(__bf16));
    float* ntp  = wsf;
    float* nsp  = wsf + 5120;
    float* gbkt = wsf + 10240;
    float* invs = wsf + 10304;
    float* ssq  = wsf + 10306;
    float* cnts = wsf + 10370;
    int* perm_t = (int*)(wsf + 10400);
    int* perm_s = (int*)(wsf + 15520);
    float* psum = wsf + 20640;

    k_sortcol<<<65, 1024, 0, stream>>>(labels, groups, ft, fs,
                                       perm_t, perm_s, cnts, psum, ssq);
    k_prep<<<2560, 256, 0, stream>>>(ft, fs, perm_t, perm_s, Tp, Sp, ntp, nsp,
                                     cnts, psum, ssq, gbkt, invs);
    k_gram_all<<<NTILES, 512, 0, stream>>>(Tp, Sp, ntp, nsp, cnts, invs, gbkt);
    k_out<<<1, 128, 0, stream>>>(cnts, gbkt, (float*)d_out);
}